// Round 1
// baseline (2066.906 us; speedup 1.0000x reference)
//
#include <hip/hip_runtime.h>
#include <hip/hip_bf16.h>
#include <math.h>

// ---------- small helpers ----------
__device__ __forceinline__ float3 f3sub(float3 a, float3 b){ return make_float3(a.x-b.x, a.y-b.y, a.z-b.z); }
__device__ __forceinline__ float3 f3nrm(float3 v){
  float n = sqrtf(v.x*v.x + v.y*v.y + v.z*v.z);
  float inv = 1.0f / fmaxf(n, 1e-8f);
  return make_float3(v.x*inv, v.y*inv, v.z*inv);
}
__device__ __forceinline__ float3 f3cross(float3 a, float3 b){
  return make_float3(a.y*b.z - a.z*b.y, a.z*b.x - a.x*b.z, a.x*b.y - a.y*b.x);
}
__device__ __forceinline__ float silu_f(float x){
  float ex = __expf(-x);
  return x * __builtin_amdgcn_rcpf(1.0f + ex);
}

// ---------- kernel 1: residue frames ----------
// u[i] = nrm(p[i+1]-p[i]); end=u[k], start=u[k+1];
// frame[k] = [nrm(u[k]-u[k+1]); nrm(cross(u[k],u[k+1])); nrm(cross(diff,cross))]
// residue_frame[n] = frame[clamp(n-1, 0, Nr-3)]
__global__ void frames_kernel(const float* __restrict__ pos, float* __restrict__ frames, int Nr){
  int n = blockIdx.x*blockDim.x + threadIdx.x;
  if (n >= Nr) return;
  int k = n - 1;
  if (k < 0) k = 0;
  int kmax = Nr - 3;
  if (k > kmax) k = kmax;
  float3 p0 = make_float3(pos[3*k+0], pos[3*k+1], pos[3*k+2]);
  float3 p1 = make_float3(pos[3*k+3], pos[3*k+4], pos[3*k+5]);
  float3 p2 = make_float3(pos[3*k+6], pos[3*k+7], pos[3*k+8]);
  float3 u0 = f3nrm(f3sub(p1,p0));   // end  = u[k]
  float3 u1 = f3nrm(f3sub(p2,p1));   // start= u[k+1]
  float3 dif = f3nrm(f3sub(u0,u1));
  float3 cr  = f3nrm(f3cross(u0,u1));
  float3 vt  = f3nrm(f3cross(dif,cr));
  float* o = frames + (size_t)n*9;
  o[0]=dif.x; o[1]=dif.y; o[2]=dif.z;
  o[3]=cr.x;  o[4]=cr.y;  o[5]=cr.z;
  o[6]=vt.x;  o[7]=vt.y;  o[8]=vt.z;
}

// ---------- kernel 2: per-edge diff + proj ----------
// proj[j] = ed.x*F[0][j] + ed.y*F[1][j] + ed.z*F[2][j]
__global__ void edgepre_kernel(const float* __restrict__ posl, const float* __restrict__ posr,
    const int* __restrict__ el, const int* __restrict__ er, const float* __restrict__ frames,
    float* __restrict__ ediff, float* __restrict__ proj, int E){
  int e = blockIdx.x*blockDim.x + threadIdx.x;
  if (e >= E) return;
  int a = el[e], r = er[e];
  float3 pa = make_float3(posl[3*a+0], posl[3*a+1], posl[3*a+2]);
  float3 pr = make_float3(posr[3*r+0], posr[3*r+1], posr[3*r+2]);
  float3 ed = f3nrm(f3sub(pa,pr));
  const float* F = frames + (size_t)r*9;
  float px = ed.x*F[0] + ed.y*F[3] + ed.z*F[6];
  float py = ed.x*F[1] + ed.y*F[4] + ed.z*F[7];
  float pz = ed.x*F[2] + ed.y*F[5] + ed.z*F[8];
  ediff[3*e+0]=ed.x; ediff[3*e+1]=ed.y; ediff[3*e+2]=ed.z;
  proj[3*e+0]=px; proj[3*e+1]=py; proj[3*e+2]=pz;
}

// ---------- kernel 3: h = silu((lig[el]+res[er]) @ W1 + b1) @ W2 + b2 ----------
#define GT 64
__global__ __launch_bounds__(256) void h_gemm_kernel(
    const float* __restrict__ lig, const float* __restrict__ res,
    const int* __restrict__ el, const int* __restrict__ er,
    const float* __restrict__ W1, const float* __restrict__ b1,
    const float* __restrict__ W2, const float* __restrict__ b2,
    float* __restrict__ hout, int E)
{
  __shared__ float sX[GT][132];
  __shared__ float sY[GT][132];
  __shared__ float sW[16][132];
  int tid = threadIdx.x;
  int e0 = blockIdx.x * GT;

  // stage X = lig[el]+res[er] (64 rows x 128)
  {
    int r = tid >> 2, p = tid & 3;
    int cb = p * 32;
    int e = e0 + r;
    if (e < E) {
      const float* lr = lig + (size_t)el[e]*128 + cb;
      const float* rr = res + (size_t)er[e]*128 + cb;
      #pragma unroll
      for (int i = 0; i < 32; i += 4) {
        float4 va = *(const float4*)(lr+i);
        float4 vb = *(const float4*)(rr+i);
        va.x += vb.x; va.y += vb.y; va.z += vb.z; va.w += vb.w;
        *(float4*)&sX[r][cb+i] = va;
      }
    } else {
      float4 z = make_float4(0.f,0.f,0.f,0.f);
      #pragma unroll
      for (int i = 0; i < 32; i += 4) *(float4*)&sX[r][cb+i] = z;
    }
  }

  int rg = tid >> 4, cg = tid & 15;
  int r0 = rg*4, c0 = cg*8;
  float acc[4][8];
  #pragma unroll
  for (int i=0;i<4;i++){
    #pragma unroll
    for (int j=0;j<8;j++) acc[i][j]=0.f;
  }

  // GEMM1: sX @ W1
  for (int kc = 0; kc < 128; kc += 16) {
    __syncthreads();
    {
      int kk = tid >> 4, cc = (tid & 15)*8;
      const float* src = W1 + (size_t)(kc+kk)*128 + cc;
      *(float4*)&sW[kk][cc]   = *(const float4*)src;
      *(float4*)&sW[kk][cc+4] = *(const float4*)(src+4);
    }
    __syncthreads();
    #pragma unroll
    for (int k4 = 0; k4 < 16; k4 += 4) {
      float xr[4][4];
      #pragma unroll
      for (int i=0;i<4;i++){
        float4 t = *(const float4*)&sX[r0+i][kc+k4];
        xr[i][0]=t.x; xr[i][1]=t.y; xr[i][2]=t.z; xr[i][3]=t.w;
      }
      #pragma unroll
      for (int kk=0;kk<4;kk++){
        float4 w0 = *(const float4*)&sW[k4+kk][c0];
        float4 w1 = *(const float4*)&sW[k4+kk][c0+4];
        float wr[8] = {w0.x,w0.y,w0.z,w0.w,w1.x,w1.y,w1.z,w1.w};
        #pragma unroll
        for (int i=0;i<4;i++){
          #pragma unroll
          for (int j=0;j<8;j++)
            acc[i][j] = fmaf(xr[i][kk], wr[j], acc[i][j]);
        }
      }
    }
  }

  // bias + silu -> sY
  {
    float bj[8];
    #pragma unroll
    for (int j=0;j<8;j++) bj[j] = b1[c0+j];
    #pragma unroll
    for (int i=0;i<4;i++){
      float v[8];
      #pragma unroll
      for (int j=0;j<8;j++){
        v[j] = silu_f(acc[i][j] + bj[j]);
        acc[i][j] = 0.f;
      }
      *(float4*)&sY[r0+i][c0]   = make_float4(v[0],v[1],v[2],v[3]);
      *(float4*)&sY[r0+i][c0+4] = make_float4(v[4],v[5],v[6],v[7]);
    }
  }

  // GEMM2: sY @ W2
  for (int kc = 0; kc < 128; kc += 16) {
    __syncthreads();  // also guarantees sY fully written before first read
    {
      int kk = tid >> 4, cc = (tid & 15)*8;
      const float* src = W2 + (size_t)(kc+kk)*128 + cc;
      *(float4*)&sW[kk][cc]   = *(const float4*)src;
      *(float4*)&sW[kk][cc+4] = *(const float4*)(src+4);
    }
    __syncthreads();
    #pragma unroll
    for (int k4 = 0; k4 < 16; k4 += 4) {
      float xr[4][4];
      #pragma unroll
      for (int i=0;i<4;i++){
        float4 t = *(const float4*)&sY[r0+i][kc+k4];
        xr[i][0]=t.x; xr[i][1]=t.y; xr[i][2]=t.z; xr[i][3]=t.w;
      }
      #pragma unroll
      for (int kk=0;kk<4;kk++){
        float4 w0 = *(const float4*)&sW[k4+kk][c0];
        float4 w1 = *(const float4*)&sW[k4+kk][c0+4];
        float wr[8] = {w0.x,w0.y,w0.z,w0.w,w1.x,w1.y,w1.z,w1.w};
        #pragma unroll
        for (int i=0;i<4;i++){
          #pragma unroll
          for (int j=0;j<8;j++)
            acc[i][j] = fmaf(xr[i][kk], wr[j], acc[i][j]);
        }
      }
    }
  }

  // + b2, store
  {
    float bj[8];
    #pragma unroll
    for (int j=0;j<8;j++) bj[j] = b2[c0+j];
    #pragma unroll
    for (int i=0;i<4;i++){
      int e = e0 + r0 + i;
      if (e < E){
        float4 o0 = make_float4(acc[i][0]+bj[0], acc[i][1]+bj[1], acc[i][2]+bj[2], acc[i][3]+bj[3]);
        float4 o1 = make_float4(acc[i][4]+bj[4], acc[i][5]+bj[5], acc[i][6]+bj[6], acc[i][7]+bj[7]);
        *(float4*)(hout + (size_t)e*128 + c0)     = o0;
        *(float4*)(hout + (size_t)e*128 + c0 + 4) = o1;
      }
    }
  }
}

// ---------- kernel 4: per-atom silu-MLP + segmented reduce ----------
// lv_new[a,c,d] = lv_old[a,c,d]*(1 + sum_e w01[e,d]) + sum_e ediff[e,c]*w02[e,d]
#define CH 8
__global__ __launch_bounds__(128) void atom_kernel(
    const float* __restrict__ hbuf, const float* __restrict__ proj, const float* __restrict__ ediff,
    const int* __restrict__ el,
    const float* __restrict__ Wa1, const float* __restrict__ ba1,
    const float* __restrict__ Wb1, const float* __restrict__ bb1,
    const float* __restrict__ Wa2, const float* __restrict__ ba2,
    const float* __restrict__ Wb2, const float* __restrict__ bb2,
    float* __restrict__ lv, int E, int layer)
{
  int a = blockIdx.x;
  int tid = threadIdx.x;
  __shared__ float sWa1[3][32], sWa2[3][32];
  __shared__ float4 sQC[32];      // {ba1, Wb1, ba2, Wb2} per q
  __shared__ float sA1[32][CH], sA2[32][CH];
  __shared__ float4 sEd[CH];      // ediff.xyz, proj0

  if (tid < 96) {
    sWa1[tid>>5][tid&31] = Wa1[tid];
    sWa2[tid>>5][tid&31] = Wa2[tid];
  }
  if (tid < 32) sQC[tid] = make_float4(ba1[tid], Wb1[tid], ba2[tid], Wb2[tid]);
  float cb1 = bb1[0], cb2 = bb2[0];

  // binary searches: estart = lower_bound(el, a), eend = lower_bound(el, a+1)
  int lo = 0, hi = E;
  while (lo < hi){ int m = (lo+hi)>>1; if (el[m] < a) lo = m+1; else hi = m; }
  int estart = lo;
  int lo2 = lo, hi2 = E;
  while (lo2 < hi2){ int m = (lo2+hi2)>>1; if (el[m] <= a) lo2 = m+1; else hi2 = m; }
  int eend = lo2;

  __syncthreads();

  float sumw = 0.f, tx = 0.f, ty = 0.f, tz = 0.f;

  for (int eb = estart; eb < eend; eb += CH) {
    int n = min(CH, eend - eb);
    __syncthreads();
    for (int idx = tid; idx < (n<<5); idx += 128) {
      int i = idx >> 5, q = idx & 31;
      int e = eb + i;
      float p0 = proj[3*e+0], p1 = proj[3*e+1], p2 = proj[3*e+2];
      sA1[q][i] = p0*sWa1[0][q] + p1*sWa1[1][q] + p2*sWa1[2][q];
      sA2[q][i] = p0*sWa2[0][q] + p1*sWa2[1][q] + p2*sWa2[2][q];
    }
    if (tid < n) {
      int e = eb + tid;
      sEd[tid] = make_float4(ediff[3*e+0], ediff[3*e+1], ediff[3*e+2], proj[3*e+0]);
    }
    __syncthreads();

    float hv[CH], ac1[CH], ac2[CH];
    #pragma unroll
    for (int i=0;i<CH;i++){
      int e = eb + i; if (e >= eend) e = eend - 1;   // clamp to stay in-bounds
      hv[i] = hbuf[(size_t)e*128 + tid];
      ac1[i] = cb1; ac2[i] = cb2;
    }
    #pragma unroll
    for (int q=0;q<32;q++){
      float4 qc = sQC[q];
      float4 a1l = *(const float4*)&sA1[q][0];
      float4 a1h = *(const float4*)&sA1[q][4];
      float4 a2l = *(const float4*)&sA2[q][0];
      float4 a2h = *(const float4*)&sA2[q][4];
      float a1r[8] = {a1l.x,a1l.y,a1l.z,a1l.w,a1h.x,a1h.y,a1h.z,a1h.w};
      float a2r[8] = {a2l.x,a2l.y,a2l.z,a2l.w,a2h.x,a2h.y,a2h.z,a2h.w};
      #pragma unroll
      for (int i=0;i<CH;i++){
        float x1 = fmaf(hv[i], a1r[i], qc.x);
        float e1 = __expf(-x1);
        ac1[i] = fmaf(x1*__builtin_amdgcn_rcpf(1.0f+e1), qc.y, ac1[i]);
        float x2 = fmaf(hv[i], a2r[i], qc.z);
        float e2 = __expf(-x2);
        ac2[i] = fmaf(x2*__builtin_amdgcn_rcpf(1.0f+e2), qc.w, ac2[i]);
      }
    }
    #pragma unroll
    for (int i=0;i<CH;i++){
      if (i < n){
        float4 ed = sEd[i];
        float w01 = ac1[i] + hv[i]*ed.w;
        float w02 = ac2[i] + hv[i]*ed.w;
        sumw += w01;
        tx = fmaf(ed.x, w02, tx);
        ty = fmaf(ed.y, w02, ty);
        tz = fmaf(ed.z, w02, tz);
      }
    }
  }

  size_t base = (size_t)a*384 + tid;
  if (layer == 0){
    lv[base      ] = tx;
    lv[base + 128] = ty;
    lv[base + 256] = tz;
  } else {
    float m = 1.0f + sumw;
    lv[base      ] = lv[base      ]*m + tx;
    lv[base + 128] = lv[base + 128]*m + ty;
    lv[base + 256] = lv[base + 256]*m + tz;
  }
}

// ---------- kernel 5: head ----------
// out[a,c] = sum_d relu(sum_k lv[a,c,k]*Wl1[k,d] + bl1[d]) * Wl2[d] + bl2 + lvin[a,c]
__global__ __launch_bounds__(128) void head_kernel(
    const float* __restrict__ lv, const float* __restrict__ Wl1, const float* __restrict__ bl1,
    const float* __restrict__ Wl2, const float* __restrict__ bl2,
    const float* __restrict__ lvin, float* __restrict__ out, int Nl)
{
  int a = blockIdx.x, d = threadIdx.x;
  __shared__ float slv[3][128];
  __shared__ float sred[2][3];
  size_t base = (size_t)a*384;
  slv[0][d] = lv[base + d];
  slv[1][d] = lv[base + 128 + d];
  slv[2][d] = lv[base + 256 + d];
  __syncthreads();
  float b = bl1[d];
  float a0 = b, a1 = b, a2 = b;
  #pragma unroll 4
  for (int k = 0; k < 128; ++k) {
    float w = Wl1[k*128 + d];
    a0 = fmaf(slv[0][k], w, a0);
    a1 = fmaf(slv[1][k], w, a1);
    a2 = fmaf(slv[2][k], w, a2);
  }
  float wl2 = Wl2[d];
  float z0 = fmaxf(a0, 0.f)*wl2;
  float z1 = fmaxf(a1, 0.f)*wl2;
  float z2 = fmaxf(a2, 0.f)*wl2;
  #pragma unroll
  for (int off = 32; off > 0; off >>= 1) {
    z0 += __shfl_down(z0, off);
    z1 += __shfl_down(z1, off);
    z2 += __shfl_down(z2, off);
  }
  int wv = d >> 6;
  if ((d & 63) == 0) { sred[wv][0]=z0; sred[wv][1]=z1; sred[wv][2]=z2; }
  __syncthreads();
  if (d == 0) {
    float bb = bl2[0];
    out[a*3+0] = sred[0][0]+sred[1][0] + bb + lvin[a*3+0];
    out[a*3+1] = sred[0][1]+sred[1][1] + bb + lvin[a*3+1];
    out[a*3+2] = sred[0][2]+sred[1][2] + bb + lvin[a*3+2];
  }
}

// ---------- launcher ----------
extern "C" void kernel_launch(void* const* d_in, const int* in_sizes, int n_in,
                              void* d_out, int out_size, void* d_ws, size_t ws_size,
                              hipStream_t stream)
{
  const float* lig   = (const float*)d_in[0];
  const float* lvin  = (const float*)d_in[1];
  const float* posl  = (const float*)d_in[2];
  const float* res   = (const float*)d_in[3];
  const float* posr  = (const float*)d_in[4];
  const int*   el    = (const int*)d_in[7];
  const int*   er    = (const int*)d_in[8];
  const float* Win1  = (const float*)d_in[9];
  const float* bin1  = (const float*)d_in[10];
  const float* Win2  = (const float*)d_in[11];
  const float* bin2  = (const float*)d_in[12];
  const float* Ws1a  = (const float*)d_in[13];
  const float* bs1a  = (const float*)d_in[14];
  const float* Ws1b  = (const float*)d_in[15];
  const float* bs1b  = (const float*)d_in[16];
  const float* Ws2a  = (const float*)d_in[17];
  const float* bs2a  = (const float*)d_in[18];
  const float* Ws2b  = (const float*)d_in[19];
  const float* bs2b  = (const float*)d_in[20];
  const float* Wl1   = (const float*)d_in[21];
  const float* bl1   = (const float*)d_in[22];
  const float* Wl2   = (const float*)d_in[23];
  const float* bl2   = (const float*)d_in[24];

  int Nl = in_sizes[2] / 3;
  int Nr = in_sizes[4] / 3;
  int E  = in_sizes[7];

  float* ws = (float*)d_ws;
  size_t off = 0;
  float* frames = ws + off; off += (((size_t)Nr*9 + 3)/4)*4;
  float* ediff  = ws + off; off += (((size_t)E*3 + 3)/4)*4;
  float* proj   = ws + off; off += (((size_t)E*3 + 3)/4)*4;
  float* hbuf   = ws + off; off += (size_t)E*128;
  float* lvbuf  = ws + off; off += (size_t)Nl*384;

  hipLaunchKernelGGL(frames_kernel, dim3((Nr+255)/256), dim3(256), 0, stream, posr, frames, Nr);
  hipLaunchKernelGGL(edgepre_kernel, dim3((E+255)/256), dim3(256), 0, stream,
                     posl, posr, el, er, frames, ediff, proj, E);
  for (int l = 0; l < 2; ++l) {
    hipLaunchKernelGGL(h_gemm_kernel, dim3((E+GT-1)/GT), dim3(256), 0, stream,
        lig, res, el, er,
        Win1 + (size_t)l*16384, bin1 + (size_t)l*128,
        Win2 + (size_t)l*16384, bin2 + (size_t)l*128,
        hbuf, E);
    hipLaunchKernelGGL(atom_kernel, dim3(Nl), dim3(128), 0, stream,
        hbuf, proj, ediff, el,
        Ws1a + (size_t)l*96, bs1a + (size_t)l*32, Ws1b + (size_t)l*32, bs1b + l,
        Ws2a + (size_t)l*96, bs2a + (size_t)l*32, Ws2b + (size_t)l*32, bs2b + l,
        lvbuf, E, l);
  }
  hipLaunchKernelGGL(head_kernel, dim3(Nl), dim3(128), 0, stream,
                     lvbuf, Wl1, bl1, Wl2, bl2, lvin, (float*)d_out, Nl);
}

// Round 2
// 776.501 us; speedup vs baseline: 2.6618x; 2.6618x over previous
//
#include <hip/hip_runtime.h>
#include <hip/hip_bf16.h>
#include <math.h>

// ---------- small helpers ----------
__device__ __forceinline__ float3 f3sub(float3 a, float3 b){ return make_float3(a.x-b.x, a.y-b.y, a.z-b.z); }
__device__ __forceinline__ float3 f3nrm(float3 v){
  float n = sqrtf(v.x*v.x + v.y*v.y + v.z*v.z);
  float inv = 1.0f / fmaxf(n, 1e-8f);
  return make_float3(v.x*inv, v.y*inv, v.z*inv);
}
__device__ __forceinline__ float3 f3cross(float3 a, float3 b){
  return make_float3(a.y*b.z - a.z*b.y, a.z*b.x - a.x*b.z, a.x*b.y - a.y*b.x);
}
__device__ __forceinline__ float silu_f(float x){
  float ex = __expf(-x);
  return x * __builtin_amdgcn_rcpf(1.0f + ex);
}

// ---------- kernel 1: residue frames ----------
__global__ void frames_kernel(const float* __restrict__ pos, float* __restrict__ frames, int Nr){
  int n = blockIdx.x*blockDim.x + threadIdx.x;
  if (n >= Nr) return;
  int k = n - 1;
  if (k < 0) k = 0;
  int kmax = Nr - 3;
  if (k > kmax) k = kmax;
  float3 p0 = make_float3(pos[3*k+0], pos[3*k+1], pos[3*k+2]);
  float3 p1 = make_float3(pos[3*k+3], pos[3*k+4], pos[3*k+5]);
  float3 p2 = make_float3(pos[3*k+6], pos[3*k+7], pos[3*k+8]);
  float3 u0 = f3nrm(f3sub(p1,p0));   // end  = u[k]
  float3 u1 = f3nrm(f3sub(p2,p1));   // start= u[k+1]
  float3 dif = f3nrm(f3sub(u0,u1));
  float3 cr  = f3nrm(f3cross(u0,u1));
  float3 vt  = f3nrm(f3cross(dif,cr));
  float* o = frames + (size_t)n*9;
  o[0]=dif.x; o[1]=dif.y; o[2]=dif.z;
  o[3]=cr.x;  o[4]=cr.y;  o[5]=cr.z;
  o[6]=vt.x;  o[7]=vt.y;  o[8]=vt.z;
}

// ---------- kernel 2: per-edge diff + proj ----------
__global__ void edgepre_kernel(const float* __restrict__ posl, const float* __restrict__ posr,
    const int* __restrict__ el, const int* __restrict__ er, const float* __restrict__ frames,
    float* __restrict__ ediff, float* __restrict__ proj, int E){
  int e = blockIdx.x*blockDim.x + threadIdx.x;
  if (e >= E) return;
  int a = el[e], r = er[e];
  float3 pa = make_float3(posl[3*a+0], posl[3*a+1], posl[3*a+2]);
  float3 pr = make_float3(posr[3*r+0], posr[3*r+1], posr[3*r+2]);
  float3 ed = f3nrm(f3sub(pa,pr));
  const float* F = frames + (size_t)r*9;
  float px = ed.x*F[0] + ed.y*F[3] + ed.z*F[6];
  float py = ed.x*F[1] + ed.y*F[4] + ed.z*F[7];
  float pz = ed.x*F[2] + ed.y*F[5] + ed.z*F[8];
  ediff[3*e+0]=ed.x; ediff[3*e+1]=ed.y; ediff[3*e+2]=ed.z;
  proj[3*e+0]=px; proj[3*e+1]=py; proj[3*e+2]=pz;
}

// ---------- kernel 3: h = silu((lig[el]+res[er]) @ W1 + b1) @ W2 + b2 -> bf16 ----------
#define GT 64
__global__ __launch_bounds__(256) void h_gemm_kernel(
    const float* __restrict__ lig, const float* __restrict__ res,
    const int* __restrict__ el, const int* __restrict__ er,
    const float* __restrict__ W1, const float* __restrict__ b1,
    const float* __restrict__ W2, const float* __restrict__ b2,
    __hip_bfloat16* __restrict__ hout, int E)
{
  __shared__ float sX[GT][132];
  __shared__ float sY[GT][132];
  __shared__ float sW[16][132];
  int tid = threadIdx.x;
  int e0 = blockIdx.x * GT;

  // stage X = lig[el]+res[er] (64 rows x 128)
  {
    int r = tid >> 2, p = tid & 3;
    int cb = p * 32;
    int e = e0 + r;
    if (e < E) {
      const float* lr = lig + (size_t)el[e]*128 + cb;
      const float* rr = res + (size_t)er[e]*128 + cb;
      #pragma unroll
      for (int i = 0; i < 32; i += 4) {
        float4 va = *(const float4*)(lr+i);
        float4 vb = *(const float4*)(rr+i);
        va.x += vb.x; va.y += vb.y; va.z += vb.z; va.w += vb.w;
        *(float4*)&sX[r][cb+i] = va;
      }
    } else {
      float4 z = make_float4(0.f,0.f,0.f,0.f);
      #pragma unroll
      for (int i = 0; i < 32; i += 4) *(float4*)&sX[r][cb+i] = z;
    }
  }

  int rg = tid >> 4, cg = tid & 15;
  int r0 = rg*4, c0 = cg*8;
  float acc[4][8];
  #pragma unroll
  for (int i=0;i<4;i++){
    #pragma unroll
    for (int j=0;j<8;j++) acc[i][j]=0.f;
  }

  // GEMM1: sX @ W1
  for (int kc = 0; kc < 128; kc += 16) {
    __syncthreads();
    {
      int kk = tid >> 4, cc = (tid & 15)*8;
      const float* src = W1 + (size_t)(kc+kk)*128 + cc;
      *(float4*)&sW[kk][cc]   = *(const float4*)src;
      *(float4*)&sW[kk][cc+4] = *(const float4*)(src+4);
    }
    __syncthreads();
    #pragma unroll
    for (int k4 = 0; k4 < 16; k4 += 4) {
      float xr[4][4];
      #pragma unroll
      for (int i=0;i<4;i++){
        float4 t = *(const float4*)&sX[r0+i][kc+k4];
        xr[i][0]=t.x; xr[i][1]=t.y; xr[i][2]=t.z; xr[i][3]=t.w;
      }
      #pragma unroll
      for (int kk=0;kk<4;kk++){
        float4 w0 = *(const float4*)&sW[k4+kk][c0];
        float4 w1 = *(const float4*)&sW[k4+kk][c0+4];
        float wr[8] = {w0.x,w0.y,w0.z,w0.w,w1.x,w1.y,w1.z,w1.w};
        #pragma unroll
        for (int i=0;i<4;i++){
          #pragma unroll
          for (int j=0;j<8;j++)
            acc[i][j] = fmaf(xr[i][kk], wr[j], acc[i][j]);
        }
      }
    }
  }

  // bias + silu -> sY
  {
    float bj[8];
    #pragma unroll
    for (int j=0;j<8;j++) bj[j] = b1[c0+j];
    #pragma unroll
    for (int i=0;i<4;i++){
      float v[8];
      #pragma unroll
      for (int j=0;j<8;j++){
        v[j] = silu_f(acc[i][j] + bj[j]);
        acc[i][j] = 0.f;
      }
      *(float4*)&sY[r0+i][c0]   = make_float4(v[0],v[1],v[2],v[3]);
      *(float4*)&sY[r0+i][c0+4] = make_float4(v[4],v[5],v[6],v[7]);
    }
  }

  // GEMM2: sY @ W2
  for (int kc = 0; kc < 128; kc += 16) {
    __syncthreads();
    {
      int kk = tid >> 4, cc = (tid & 15)*8;
      const float* src = W2 + (size_t)(kc+kk)*128 + cc;
      *(float4*)&sW[kk][cc]   = *(const float4*)src;
      *(float4*)&sW[kk][cc+4] = *(const float4*)(src+4);
    }
    __syncthreads();
    #pragma unroll
    for (int k4 = 0; k4 < 16; k4 += 4) {
      float xr[4][4];
      #pragma unroll
      for (int i=0;i<4;i++){
        float4 t = *(const float4*)&sY[r0+i][kc+k4];
        xr[i][0]=t.x; xr[i][1]=t.y; xr[i][2]=t.z; xr[i][3]=t.w;
      }
      #pragma unroll
      for (int kk=0;kk<4;kk++){
        float4 w0 = *(const float4*)&sW[k4+kk][c0];
        float4 w1 = *(const float4*)&sW[k4+kk][c0+4];
        float wr[8] = {w0.x,w0.y,w0.z,w0.w,w1.x,w1.y,w1.z,w1.w};
        #pragma unroll
        for (int i=0;i<4;i++){
          #pragma unroll
          for (int j=0;j<8;j++)
            acc[i][j] = fmaf(xr[i][kk], wr[j], acc[i][j]);
        }
      }
    }
  }

  // + b2, convert bf16, store
  {
    float bj[8];
    #pragma unroll
    for (int j=0;j<8;j++) bj[j] = b2[c0+j];
    #pragma unroll
    for (int i=0;i<4;i++){
      int e = e0 + r0 + i;
      if (e < E){
        union { __hip_bfloat16 b[8]; uint4 u; } cv;
        #pragma unroll
        for (int j=0;j<8;j++) cv.b[j] = __float2bfloat16(acc[i][j]+bj[j]);
        *(uint4*)(hout + (size_t)e*128 + c0) = cv.u;
      }
    }
  }
}

// ---------- kernel 4a: edge-parallel dual-silu MLP -> w01,w02 (bf16) ----------
// w01[e,d] = sum_q silu(h*A1[e,q]+ba1[q])*Wb1[q] + bb1 + h*proj0[e]
__global__ __launch_bounds__(256) void edgew_kernel(
    const __hip_bfloat16* __restrict__ hbuf, const float* __restrict__ proj,
    const float* __restrict__ Wa1, const float* __restrict__ ba1,
    const float* __restrict__ Wb1, const float* __restrict__ bb1,
    const float* __restrict__ Wa2, const float* __restrict__ ba2,
    const float* __restrict__ Wb2, const float* __restrict__ bb2,
    __hip_bfloat16* __restrict__ w01, __hip_bfloat16* __restrict__ w02, int E)
{
  __shared__ float sA1[2][32], sA2[2][32];
  __shared__ float4 sQC[32];       // {ba1, Wb1, ba2, Wb2} per q
  __shared__ float sP0[2];
  int tid = threadIdx.x;
  int e0 = blockIdx.x*2;
  if (tid < 64){
    int ei = tid>>5, q = tid&31;
    int e = e0+ei; if (e > E-1) e = E-1;
    float p0=proj[3*e+0], p1=proj[3*e+1], p2=proj[3*e+2];
    sA1[ei][q] = p0*Wa1[q] + p1*Wa1[32+q] + p2*Wa1[64+q];
    sA2[ei][q] = p0*Wa2[q] + p1*Wa2[32+q] + p2*Wa2[64+q];
    if (q==0) sP0[ei] = p0;
  } else if (tid < 96){
    int q = tid-64;
    sQC[q] = make_float4(ba1[q], Wb1[q], ba2[q], Wb2[q]);
  }
  __syncthreads();
  int ei = tid>>7, d = tid&127;
  int e = e0+ei;
  if (e >= E) return;
  float h = __bfloat162float(hbuf[(size_t)e*128+d]);
  float ac1 = bb1[0], ac2 = bb2[0];
  #pragma unroll
  for (int q=0;q<32;q++){
    float4 qc = sQC[q];
    float a1 = sA1[ei][q], a2 = sA2[ei][q];
    float x1 = fmaf(h, a1, qc.x);
    float s1 = x1*__builtin_amdgcn_rcpf(1.0f+__expf(-x1));
    ac1 = fmaf(s1, qc.y, ac1);
    float x2 = fmaf(h, a2, qc.z);
    float s2 = x2*__builtin_amdgcn_rcpf(1.0f+__expf(-x2));
    ac2 = fmaf(s2, qc.w, ac2);
  }
  float hp = h*sP0[ei];
  w01[(size_t)e*128+d] = __float2bfloat16(ac1+hp);
  w02[(size_t)e*128+d] = __float2bfloat16(ac2+hp);
}

// ---------- kernel 4b: per-atom segmented reduce + lv update ----------
// lv_new[a,c,d] = lv_old[a,c,d]*(1 + sum_e w01[e,d]) + sum_e ediff[e,c]*w02[e,d]
__global__ __launch_bounds__(128) void reduce_kernel(
    const __hip_bfloat16* __restrict__ w01, const __hip_bfloat16* __restrict__ w02,
    const float* __restrict__ ediff, const int* __restrict__ el,
    float* __restrict__ lv, int E, int layer)
{
  int a = blockIdx.x;
  int d = threadIdx.x;

  int lo = 0, hi = E;
  while (lo < hi){ int m = (lo+hi)>>1; if (el[m] < a) lo = m+1; else hi = m; }
  int estart = lo;
  int lo2 = lo, hi2 = E;
  while (lo2 < hi2){ int m = (lo2+hi2)>>1; if (el[m] <= a) lo2 = m+1; else hi2 = m; }
  int eend = lo2;

  float sumw = 0.f, tx = 0.f, ty = 0.f, tz = 0.f;
  for (int e = estart; e < eend; ++e){
    float w1 = __bfloat162float(w01[(size_t)e*128 + d]);
    float w2 = __bfloat162float(w02[(size_t)e*128 + d]);
    float ex = ediff[3*e+0], ey = ediff[3*e+1], ez = ediff[3*e+2];
    sumw += w1;
    tx = fmaf(ex, w2, tx);
    ty = fmaf(ey, w2, ty);
    tz = fmaf(ez, w2, tz);
  }

  size_t base = (size_t)a*384 + d;
  if (layer == 0){
    lv[base      ] = tx;
    lv[base + 128] = ty;
    lv[base + 256] = tz;
  } else {
    float m = 1.0f + sumw;
    lv[base      ] = lv[base      ]*m + tx;
    lv[base + 128] = lv[base + 128]*m + ty;
    lv[base + 256] = lv[base + 256]*m + tz;
  }
}

// ---------- kernel 5: head ----------
__global__ __launch_bounds__(128) void head_kernel(
    const float* __restrict__ lv, const float* __restrict__ Wl1, const float* __restrict__ bl1,
    const float* __restrict__ Wl2, const float* __restrict__ bl2,
    const float* __restrict__ lvin, float* __restrict__ out, int Nl)
{
  int a = blockIdx.x, d = threadIdx.x;
  __shared__ float slv[3][128];
  __shared__ float sred[2][3];
  size_t base = (size_t)a*384;
  slv[0][d] = lv[base + d];
  slv[1][d] = lv[base + 128 + d];
  slv[2][d] = lv[base + 256 + d];
  __syncthreads();
  float b = bl1[d];
  float a0 = b, a1 = b, a2 = b;
  #pragma unroll 4
  for (int k = 0; k < 128; ++k) {
    float w = Wl1[k*128 + d];
    a0 = fmaf(slv[0][k], w, a0);
    a1 = fmaf(slv[1][k], w, a1);
    a2 = fmaf(slv[2][k], w, a2);
  }
  float wl2 = Wl2[d];
  float z0 = fmaxf(a0, 0.f)*wl2;
  float z1 = fmaxf(a1, 0.f)*wl2;
  float z2 = fmaxf(a2, 0.f)*wl2;
  #pragma unroll
  for (int off = 32; off > 0; off >>= 1) {
    z0 += __shfl_down(z0, off);
    z1 += __shfl_down(z1, off);
    z2 += __shfl_down(z2, off);
  }
  int wv = d >> 6;
  if ((d & 63) == 0) { sred[wv][0]=z0; sred[wv][1]=z1; sred[wv][2]=z2; }
  __syncthreads();
  if (d == 0) {
    float bb = bl2[0];
    out[a*3+0] = sred[0][0]+sred[1][0] + bb + lvin[a*3+0];
    out[a*3+1] = sred[0][1]+sred[1][1] + bb + lvin[a*3+1];
    out[a*3+2] = sred[0][2]+sred[1][2] + bb + lvin[a*3+2];
  }
}

// ---------- launcher ----------
extern "C" void kernel_launch(void* const* d_in, const int* in_sizes, int n_in,
                              void* d_out, int out_size, void* d_ws, size_t ws_size,
                              hipStream_t stream)
{
  const float* lig   = (const float*)d_in[0];
  const float* lvin  = (const float*)d_in[1];
  const float* posl  = (const float*)d_in[2];
  const float* res   = (const float*)d_in[3];
  const float* posr  = (const float*)d_in[4];
  const int*   el    = (const int*)d_in[7];
  const int*   er    = (const int*)d_in[8];
  const float* Win1  = (const float*)d_in[9];
  const float* bin1  = (const float*)d_in[10];
  const float* Win2  = (const float*)d_in[11];
  const float* bin2  = (const float*)d_in[12];
  const float* Ws1a  = (const float*)d_in[13];
  const float* bs1a  = (const float*)d_in[14];
  const float* Ws1b  = (const float*)d_in[15];
  const float* bs1b  = (const float*)d_in[16];
  const float* Ws2a  = (const float*)d_in[17];
  const float* bs2a  = (const float*)d_in[18];
  const float* Ws2b  = (const float*)d_in[19];
  const float* bs2b  = (const float*)d_in[20];
  const float* Wl1   = (const float*)d_in[21];
  const float* bl1   = (const float*)d_in[22];
  const float* Wl2   = (const float*)d_in[23];
  const float* bl2   = (const float*)d_in[24];

  int Nl = in_sizes[2] / 3;
  int Nr = in_sizes[4] / 3;
  int E  = in_sizes[7];

  char* wsb = (char*)d_ws;
  size_t off = 0;
  auto carve = [&](size_t bytes) -> char* {
    char* p = wsb + off;
    off += (bytes + 255) & ~(size_t)255;
    return p;
  };
  float* frames = (float*)carve((size_t)Nr*9*4);
  float* ediff  = (float*)carve((size_t)E*3*4);
  float* proj   = (float*)carve((size_t)E*3*4);
  __hip_bfloat16* hbuf = (__hip_bfloat16*)carve((size_t)E*128*2);
  __hip_bfloat16* w01  = (__hip_bfloat16*)carve((size_t)E*128*2);
  __hip_bfloat16* w02  = (__hip_bfloat16*)carve((size_t)E*128*2);
  float* lvbuf  = (float*)carve((size_t)Nl*384*4);

  hipLaunchKernelGGL(frames_kernel, dim3((Nr+255)/256), dim3(256), 0, stream, posr, frames, Nr);
  hipLaunchKernelGGL(edgepre_kernel, dim3((E+255)/256), dim3(256), 0, stream,
                     posl, posr, el, er, frames, ediff, proj, E);
  for (int l = 0; l < 2; ++l) {
    hipLaunchKernelGGL(h_gemm_kernel, dim3((E+GT-1)/GT), dim3(256), 0, stream,
        lig, res, el, er,
        Win1 + (size_t)l*16384, bin1 + (size_t)l*128,
        Win2 + (size_t)l*16384, bin2 + (size_t)l*128,
        hbuf, E);
    hipLaunchKernelGGL(edgew_kernel, dim3((E+1)/2), dim3(256), 0, stream,
        hbuf, proj,
        Ws1a + (size_t)l*96, bs1a + (size_t)l*32, Ws1b + (size_t)l*32, bs1b + l,
        Ws2a + (size_t)l*96, bs2a + (size_t)l*32, Ws2b + (size_t)l*32, bs2b + l,
        w01, w02, E);
    hipLaunchKernelGGL(reduce_kernel, dim3(Nl), dim3(128), 0, stream,
        w01, w02, ediff, el, lvbuf, E, l);
  }
  hipLaunchKernelGGL(head_kernel, dim3(Nl), dim3(128), 0, stream,
                     lvbuf, Wl1, bl1, Wl2, bl2, lvin, (float*)d_out, Nl);
}

// Round 3
// 695.811 us; speedup vs baseline: 2.9705x; 1.1160x over previous
//
#include <hip/hip_runtime.h>
#include <hip/hip_bf16.h>
#include <math.h>

// ---------- small helpers ----------
__device__ __forceinline__ float3 f3sub(float3 a, float3 b){ return make_float3(a.x-b.x, a.y-b.y, a.z-b.z); }
__device__ __forceinline__ float3 f3nrm(float3 v){
  float n = sqrtf(v.x*v.x + v.y*v.y + v.z*v.z);
  float inv = 1.0f / fmaxf(n, 1e-8f);
  return make_float3(v.x*inv, v.y*inv, v.z*inv);
}
__device__ __forceinline__ float3 f3cross(float3 a, float3 b){
  return make_float3(a.y*b.z - a.z*b.y, a.z*b.x - a.x*b.z, a.x*b.y - a.y*b.x);
}
__device__ __forceinline__ float silu_f(float x){
  float ex = __expf(-x);
  return x * __builtin_amdgcn_rcpf(1.0f + ex);
}

// ---------- kernel 1: residue frames ----------
__global__ void frames_kernel(const float* __restrict__ pos, float* __restrict__ frames, int Nr){
  int n = blockIdx.x*blockDim.x + threadIdx.x;
  if (n >= Nr) return;
  int k = n - 1;
  if (k < 0) k = 0;
  int kmax = Nr - 3;
  if (k > kmax) k = kmax;
  float3 p0 = make_float3(pos[3*k+0], pos[3*k+1], pos[3*k+2]);
  float3 p1 = make_float3(pos[3*k+3], pos[3*k+4], pos[3*k+5]);
  float3 p2 = make_float3(pos[3*k+6], pos[3*k+7], pos[3*k+8]);
  float3 u0 = f3nrm(f3sub(p1,p0));   // end  = u[k]
  float3 u1 = f3nrm(f3sub(p2,p1));   // start= u[k+1]
  float3 dif = f3nrm(f3sub(u0,u1));
  float3 cr  = f3nrm(f3cross(u0,u1));
  float3 vt  = f3nrm(f3cross(dif,cr));
  float* o = frames + (size_t)n*9;
  o[0]=dif.x; o[1]=dif.y; o[2]=dif.z;
  o[3]=cr.x;  o[4]=cr.y;  o[5]=cr.z;
  o[6]=vt.x;  o[7]=vt.y;  o[8]=vt.z;
}

// ---------- kernel 2: per-edge diff + proj ----------
__global__ void edgepre_kernel(const float* __restrict__ posl, const float* __restrict__ posr,
    const int* __restrict__ el, const int* __restrict__ er, const float* __restrict__ frames,
    float* __restrict__ ediff, float* __restrict__ proj, int E){
  int e = blockIdx.x*blockDim.x + threadIdx.x;
  if (e >= E) return;
  int a = el[e], r = er[e];
  float3 pa = make_float3(posl[3*a+0], posl[3*a+1], posl[3*a+2]);
  float3 pr = make_float3(posr[3*r+0], posr[3*r+1], posr[3*r+2]);
  float3 ed = f3nrm(f3sub(pa,pr));
  const float* F = frames + (size_t)r*9;
  float px = ed.x*F[0] + ed.y*F[3] + ed.z*F[6];
  float py = ed.x*F[1] + ed.y*F[4] + ed.z*F[7];
  float pz = ed.x*F[2] + ed.y*F[5] + ed.z*F[8];
  ediff[3*e+0]=ed.x; ediff[3*e+1]=ed.y; ediff[3*e+2]=ed.z;
  proj[3*e+0]=px; proj[3*e+1]=py; proj[3*e+2]=pz;
}

// ---------- kernel 3: h = silu((lig[el]+res[er]) @ W1 + b1) @ W2 + b2 -> bf16 ----------
#define GT 64
__global__ __launch_bounds__(256) void h_gemm_kernel(
    const float* __restrict__ lig, const float* __restrict__ res,
    const int* __restrict__ el, const int* __restrict__ er,
    const float* __restrict__ W1, const float* __restrict__ b1,
    const float* __restrict__ W2, const float* __restrict__ b2,
    __hip_bfloat16* __restrict__ hout, int E)
{
  __shared__ float sX[GT][132];
  __shared__ float sY[GT][132];
  __shared__ float sW[16][132];
  int tid = threadIdx.x;
  int e0 = blockIdx.x * GT;

  {
    int r = tid >> 2, p = tid & 3;
    int cb = p * 32;
    int e = e0 + r;
    if (e < E) {
      const float* lr = lig + (size_t)el[e]*128 + cb;
      const float* rr = res + (size_t)er[e]*128 + cb;
      #pragma unroll
      for (int i = 0; i < 32; i += 4) {
        float4 va = *(const float4*)(lr+i);
        float4 vb = *(const float4*)(rr+i);
        va.x += vb.x; va.y += vb.y; va.z += vb.z; va.w += vb.w;
        *(float4*)&sX[r][cb+i] = va;
      }
    } else {
      float4 z = make_float4(0.f,0.f,0.f,0.f);
      #pragma unroll
      for (int i = 0; i < 32; i += 4) *(float4*)&sX[r][cb+i] = z;
    }
  }

  int rg = tid >> 4, cg = tid & 15;
  int r0 = rg*4, c0 = cg*8;
  float acc[4][8];
  #pragma unroll
  for (int i=0;i<4;i++){
    #pragma unroll
    for (int j=0;j<8;j++) acc[i][j]=0.f;
  }

  // GEMM1: sX @ W1
  for (int kc = 0; kc < 128; kc += 16) {
    __syncthreads();
    {
      int kk = tid >> 4, cc = (tid & 15)*8;
      const float* src = W1 + (size_t)(kc+kk)*128 + cc;
      *(float4*)&sW[kk][cc]   = *(const float4*)src;
      *(float4*)&sW[kk][cc+4] = *(const float4*)(src+4);
    }
    __syncthreads();
    #pragma unroll
    for (int k4 = 0; k4 < 16; k4 += 4) {
      float xr[4][4];
      #pragma unroll
      for (int i=0;i<4;i++){
        float4 t = *(const float4*)&sX[r0+i][kc+k4];
        xr[i][0]=t.x; xr[i][1]=t.y; xr[i][2]=t.z; xr[i][3]=t.w;
      }
      #pragma unroll
      for (int kk=0;kk<4;kk++){
        float4 w0 = *(const float4*)&sW[k4+kk][c0];
        float4 w1 = *(const float4*)&sW[k4+kk][c0+4];
        float wr[8] = {w0.x,w0.y,w0.z,w0.w,w1.x,w1.y,w1.z,w1.w};
        #pragma unroll
        for (int i=0;i<4;i++){
          #pragma unroll
          for (int j=0;j<8;j++)
            acc[i][j] = fmaf(xr[i][kk], wr[j], acc[i][j]);
        }
      }
    }
  }

  // bias + silu -> sY
  {
    float bj[8];
    #pragma unroll
    for (int j=0;j<8;j++) bj[j] = b1[c0+j];
    #pragma unroll
    for (int i=0;i<4;i++){
      float v[8];
      #pragma unroll
      for (int j=0;j<8;j++){
        v[j] = silu_f(acc[i][j] + bj[j]);
        acc[i][j] = 0.f;
      }
      *(float4*)&sY[r0+i][c0]   = make_float4(v[0],v[1],v[2],v[3]);
      *(float4*)&sY[r0+i][c0+4] = make_float4(v[4],v[5],v[6],v[7]);
    }
  }

  // GEMM2: sY @ W2
  for (int kc = 0; kc < 128; kc += 16) {
    __syncthreads();
    {
      int kk = tid >> 4, cc = (tid & 15)*8;
      const float* src = W2 + (size_t)(kc+kk)*128 + cc;
      *(float4*)&sW[kk][cc]   = *(const float4*)src;
      *(float4*)&sW[kk][cc+4] = *(const float4*)(src+4);
    }
    __syncthreads();
    #pragma unroll
    for (int k4 = 0; k4 < 16; k4 += 4) {
      float xr[4][4];
      #pragma unroll
      for (int i=0;i<4;i++){
        float4 t = *(const float4*)&sY[r0+i][kc+k4];
        xr[i][0]=t.x; xr[i][1]=t.y; xr[i][2]=t.z; xr[i][3]=t.w;
      }
      #pragma unroll
      for (int kk=0;kk<4;kk++){
        float4 w0 = *(const float4*)&sW[k4+kk][c0];
        float4 w1 = *(const float4*)&sW[k4+kk][c0+4];
        float wr[8] = {w0.x,w0.y,w0.z,w0.w,w1.x,w1.y,w1.z,w1.w};
        #pragma unroll
        for (int i=0;i<4;i++){
          #pragma unroll
          for (int j=0;j<8;j++)
            acc[i][j] = fmaf(xr[i][kk], wr[j], acc[i][j]);
        }
      }
    }
  }

  {
    float bj[8];
    #pragma unroll
    for (int j=0;j<8;j++) bj[j] = b2[c0+j];
    #pragma unroll
    for (int i=0;i<4;i++){
      int e = e0 + r0 + i;
      if (e < E){
        union { __hip_bfloat16 b[8]; uint4 u; } cv;
        #pragma unroll
        for (int j=0;j<8;j++) cv.b[j] = __float2bfloat16(acc[i][j]+bj[j]);
        *(uint4*)(hout + (size_t)e*128 + c0) = cv.u;
      }
    }
  }
}

// ---------- kernel 4a: per-edge Hermite-spline of f(h) = sum_q silu(h*A_q+b_q)*w_q ----------
// w01[e,d] = f1(h[e,d]) + bb1 + h*proj0 ; same for branch 2.
// Per edge: h-range from its own 128 values (out-of-range impossible),
// 33 exact (f, f') nodes, 32 Hermite-cubic segments, then 128 cheap evals.
#define NI 32
#define NN 33
__global__ __launch_bounds__(256) void edgew_kernel(
    const __hip_bfloat16* __restrict__ hbuf, const float* __restrict__ proj,
    const float* __restrict__ Wa1, const float* __restrict__ ba1,
    const float* __restrict__ Wb1, const float* __restrict__ bb1,
    const float* __restrict__ Wa2, const float* __restrict__ ba2,
    const float* __restrict__ Wb2, const float* __restrict__ bb2,
    __hip_bfloat16* __restrict__ w01, __hip_bfloat16* __restrict__ w02, int E)
{
  __shared__ float sA[2][2][32];          // [branch][edge][q]
  __shared__ float sBA[2][32], sWB[2][32];// [branch][q] layer consts
  __shared__ float sNF[2][2][NN];         // [edge][branch][node] f
  __shared__ float sND[2][2][NN];         // f'
  __shared__ float4 sCo[2][2][NI];        // [edge][branch][interval] cubic coeffs
  __shared__ float sMin[4], sMax[4];
  __shared__ float sScal[2][4];           // h0, invD, D, proj0

  int tid = threadIdx.x;
  int ei  = tid >> 7;            // edge slot in block
  int d   = tid & 127;
  int e   = blockIdx.x*2 + ei; if (e >= E) e = E-1;   // clamp: dup work, benign dup writes

  // phase 1: load h, per-wave min/max (each wave belongs to one edge)
  float h = __bfloat162float(hbuf[(size_t)e*128 + d]);
  float mn = h, mx = h;
  #pragma unroll
  for (int o = 32; o > 0; o >>= 1){
    mn = fminf(mn, __shfl_xor(mn, o));
    mx = fmaxf(mx, __shfl_xor(mx, o));
  }
  int wv = tid >> 6;
  if ((tid & 63) == 0){ sMin[wv] = mn; sMax[wv] = mx; }
  __syncthreads();

  // phase 1b: stage per-edge A, layer consts, per-edge scalars
  if (tid < 128){
    int ee = tid >> 6, bq = tid & 63, br = bq >> 5, q = bq & 31;
    int e2 = blockIdx.x*2 + ee; if (e2 >= E) e2 = E-1;
    const float* Wa = br ? Wa2 : Wa1;
    float p0 = proj[3*e2], p1 = proj[3*e2+1], p2 = proj[3*e2+2];
    sA[br][ee][q] = p0*Wa[q] + p1*Wa[32+q] + p2*Wa[64+q];
  } else {
    int t2 = tid - 128;
    if (t2 < 64){
      int br = t2 >> 5, q = t2 & 31;
      sBA[br][q] = br ? ba2[q] : ba1[q];
      sWB[br][q] = br ? Wb2[q] : Wb1[q];
    } else if (t2 < 66){
      int ee = t2 - 64;
      float mn2 = fminf(sMin[2*ee], sMin[2*ee+1]);
      float mx2 = fmaxf(sMax[2*ee], sMax[2*ee+1]);
      float range = fmaxf(mx2 - mn2, 1e-3f);
      float Dv = range * (1.0f/NI);
      int e2 = blockIdx.x*2 + ee; if (e2 >= E) e2 = E-1;
      sScal[ee][0] = mn2;
      sScal[ee][1] = 1.0f / Dv;
      sScal[ee][2] = Dv;
      sScal[ee][3] = proj[3*e2];
    }
  }
  __syncthreads();

  // phase 2: exact f, f' at 33 nodes (per edge: 2 waves; wave = one branch; lane = node)
  {
    int t = tid & 127, br = t >> 6, node = t & 63;
    if (node < NN){
      float h0 = sScal[ei][0], Dv = sScal[ei][2];
      float hn = fmaf((float)node, Dv, h0);
      float f = 0.f, fd = 0.f;
      #pragma unroll 4
      for (int q = 0; q < 32; ++q){
        float a = sA[br][ei][q], b = sBA[br][q], w = sWB[br][q];
        float x  = fmaf(hn, a, b);
        float ex = __expf(-x);
        float sg = __builtin_amdgcn_rcpf(1.0f + ex);   // sigmoid
        f  = fmaf(w, x*sg, f);                          // + w*silu
        float sp = sg * fmaf(x, 1.0f - sg, 1.0f);       // silu'
        fd = fmaf(w*a, sp, fd);
      }
      sNF[ei][br][node] = f;
      sND[ei][br][node] = fd;
    }
  }
  __syncthreads();

  // phase 2.5: cubic coeffs per interval (value(s) = c0 + c1 s + c2 s^2 + c3 s^3)
  if (tid < 2*2*NI){
    int ee = tid >> 6, rest = tid & 63, br = rest >> 5, i = rest & 31;
    float Dv = sScal[ee][2];
    float f0 = sNF[ee][br][i],   f1 = sNF[ee][br][i+1];
    float d0 = sND[ee][br][i]*Dv, d1 = sND[ee][br][i+1]*Dv;
    float bb = br ? bb2[0] : bb1[0];
    float df = f1 - f0;
    sCo[ee][br][i] = make_float4(f0 + bb, d0, 3.f*df - 2.f*d0 - d1, d0 + d1 - 2.f*df);
  }
  __syncthreads();

  // phase 3: evaluate both branches for this (e,d)
  {
    float h0 = sScal[ei][0], invD = sScal[ei][1], p0v = sScal[ei][3];
    float sf = (h - h0) * invD;
    float fi = floorf(sf);
    int i = (int)fi; i = i < 0 ? 0 : (i > NI-1 ? NI-1 : i);
    float s = sf - (float)i;
    float4 C1 = sCo[ei][0][i];
    float4 C2 = sCo[ei][1][i];
    float v1 = fmaf(fmaf(fmaf(C1.w, s, C1.z), s, C1.y), s, C1.x);
    float v2 = fmaf(fmaf(fmaf(C2.w, s, C2.z), s, C2.y), s, C2.x);
    float hp = h * p0v;
    w01[(size_t)e*128 + d] = __float2bfloat16(v1 + hp);
    w02[(size_t)e*128 + d] = __float2bfloat16(v2 + hp);
  }
}

// ---------- kernel 4b: per-atom segmented reduce + lv update ----------
__global__ __launch_bounds__(128) void reduce_kernel(
    const __hip_bfloat16* __restrict__ w01, const __hip_bfloat16* __restrict__ w02,
    const float* __restrict__ ediff, const int* __restrict__ el,
    float* __restrict__ lv, int E, int layer)
{
  int a = blockIdx.x;
  int d = threadIdx.x;

  int lo = 0, hi = E;
  while (lo < hi){ int m = (lo+hi)>>1; if (el[m] < a) lo = m+1; else hi = m; }
  int estart = lo;
  int lo2 = lo, hi2 = E;
  while (lo2 < hi2){ int m = (lo2+hi2)>>1; if (el[m] <= a) lo2 = m+1; else hi2 = m; }
  int eend = lo2;

  float sumw = 0.f, tx = 0.f, ty = 0.f, tz = 0.f;
  for (int e = estart; e < eend; ++e){
    float w1 = __bfloat162float(w01[(size_t)e*128 + d]);
    float w2 = __bfloat162float(w02[(size_t)e*128 + d]);
    float ex = ediff[3*e+0], ey = ediff[3*e+1], ez = ediff[3*e+2];
    sumw += w1;
    tx = fmaf(ex, w2, tx);
    ty = fmaf(ey, w2, ty);
    tz = fmaf(ez, w2, tz);
  }

  size_t base = (size_t)a*384 + d;
  if (layer == 0){
    lv[base      ] = tx;
    lv[base + 128] = ty;
    lv[base + 256] = tz;
  } else {
    float m = 1.0f + sumw;
    lv[base      ] = lv[base      ]*m + tx;
    lv[base + 128] = lv[base + 128]*m + ty;
    lv[base + 256] = lv[base + 256]*m + tz;
  }
}

// ---------- kernel 5: head ----------
__global__ __launch_bounds__(128) void head_kernel(
    const float* __restrict__ lv, const float* __restrict__ Wl1, const float* __restrict__ bl1,
    const float* __restrict__ Wl2, const float* __restrict__ bl2,
    const float* __restrict__ lvin, float* __restrict__ out, int Nl)
{
  int a = blockIdx.x, d = threadIdx.x;
  __shared__ float slv[3][128];
  __shared__ float sred[2][3];
  size_t base = (size_t)a*384;
  slv[0][d] = lv[base + d];
  slv[1][d] = lv[base + 128 + d];
  slv[2][d] = lv[base + 256 + d];
  __syncthreads();
  float b = bl1[d];
  float a0 = b, a1 = b, a2 = b;
  #pragma unroll 4
  for (int k = 0; k < 128; ++k) {
    float w = Wl1[k*128 + d];
    a0 = fmaf(slv[0][k], w, a0);
    a1 = fmaf(slv[1][k], w, a1);
    a2 = fmaf(slv[2][k], w, a2);
  }
  float wl2 = Wl2[d];
  float z0 = fmaxf(a0, 0.f)*wl2;
  float z1 = fmaxf(a1, 0.f)*wl2;
  float z2 = fmaxf(a2, 0.f)*wl2;
  #pragma unroll
  for (int off = 32; off > 0; off >>= 1) {
    z0 += __shfl_down(z0, off);
    z1 += __shfl_down(z1, off);
    z2 += __shfl_down(z2, off);
  }
  int wv = d >> 6;
  if ((d & 63) == 0) { sred[wv][0]=z0; sred[wv][1]=z1; sred[wv][2]=z2; }
  __syncthreads();
  if (d == 0) {
    float bb = bl2[0];
    out[a*3+0] = sred[0][0]+sred[1][0] + bb + lvin[a*3+0];
    out[a*3+1] = sred[0][1]+sred[1][1] + bb + lvin[a*3+1];
    out[a*3+2] = sred[0][2]+sred[1][2] + bb + lvin[a*3+2];
  }
}

// ---------- launcher ----------
extern "C" void kernel_launch(void* const* d_in, const int* in_sizes, int n_in,
                              void* d_out, int out_size, void* d_ws, size_t ws_size,
                              hipStream_t stream)
{
  const float* lig   = (const float*)d_in[0];
  const float* lvin  = (const float*)d_in[1];
  const float* posl  = (const float*)d_in[2];
  const float* res   = (const float*)d_in[3];
  const float* posr  = (const float*)d_in[4];
  const int*   el    = (const int*)d_in[7];
  const int*   er    = (const int*)d_in[8];
  const float* Win1  = (const float*)d_in[9];
  const float* bin1  = (const float*)d_in[10];
  const float* Win2  = (const float*)d_in[11];
  const float* bin2  = (const float*)d_in[12];
  const float* Ws1a  = (const float*)d_in[13];
  const float* bs1a  = (const float*)d_in[14];
  const float* Ws1b  = (const float*)d_in[15];
  const float* bs1b  = (const float*)d_in[16];
  const float* Ws2a  = (const float*)d_in[17];
  const float* bs2a  = (const float*)d_in[18];
  const float* Ws2b  = (const float*)d_in[19];
  const float* bs2b  = (const float*)d_in[20];
  const float* Wl1   = (const float*)d_in[21];
  const float* bl1   = (const float*)d_in[22];
  const float* Wl2   = (const float*)d_in[23];
  const float* bl2   = (const float*)d_in[24];

  int Nl = in_sizes[2] / 3;
  int Nr = in_sizes[4] / 3;
  int E  = in_sizes[7];

  char* wsb = (char*)d_ws;
  size_t off = 0;
  auto carve = [&](size_t bytes) -> char* {
    char* p = wsb + off;
    off += (bytes + 255) & ~(size_t)255;
    return p;
  };
  float* frames = (float*)carve((size_t)Nr*9*4);
  float* ediff  = (float*)carve((size_t)E*3*4);
  float* proj   = (float*)carve((size_t)E*3*4);
  __hip_bfloat16* hbuf = (__hip_bfloat16*)carve((size_t)E*128*2);
  __hip_bfloat16* w01  = (__hip_bfloat16*)carve((size_t)E*128*2);
  __hip_bfloat16* w02  = (__hip_bfloat16*)carve((size_t)E*128*2);
  float* lvbuf  = (float*)carve((size_t)Nl*384*4);

  hipLaunchKernelGGL(frames_kernel, dim3((Nr+255)/256), dim3(256), 0, stream, posr, frames, Nr);
  hipLaunchKernelGGL(edgepre_kernel, dim3((E+255)/256), dim3(256), 0, stream,
                     posl, posr, el, er, frames, ediff, proj, E);
  for (int l = 0; l < 2; ++l) {
    hipLaunchKernelGGL(h_gemm_kernel, dim3((E+GT-1)/GT), dim3(256), 0, stream,
        lig, res, el, er,
        Win1 + (size_t)l*16384, bin1 + (size_t)l*128,
        Win2 + (size_t)l*16384, bin2 + (size_t)l*128,
        hbuf, E);
    hipLaunchKernelGGL(edgew_kernel, dim3((E+1)/2), dim3(256), 0, stream,
        hbuf, proj,
        Ws1a + (size_t)l*96, bs1a + (size_t)l*32, Ws1b + (size_t)l*32, bs1b + l,
        Ws2a + (size_t)l*96, bs2a + (size_t)l*32, Ws2b + (size_t)l*32, bs2b + l,
        w01, w02, E);
    hipLaunchKernelGGL(reduce_kernel, dim3(Nl), dim3(128), 0, stream,
        w01, w02, ediff, el, lvbuf, E, l);
  }
  hipLaunchKernelGGL(head_kernel, dim3(Nl), dim3(128), 0, stream,
                     lvbuf, Wl1, bl1, Wl2, bl2, lvin, (float*)d_out, Nl);
}

// Round 5
// 435.954 us; speedup vs baseline: 4.7411x; 1.5961x over previous
//
#include <hip/hip_runtime.h>
#include <hip/hip_bf16.h>
#include <math.h>

// ---------- small helpers ----------
__device__ __forceinline__ float3 f3sub(float3 a, float3 b){ return make_float3(a.x-b.x, a.y-b.y, a.z-b.z); }
__device__ __forceinline__ float3 f3nrm(float3 v){
  float n = sqrtf(v.x*v.x + v.y*v.y + v.z*v.z);
  float inv = 1.0f / fmaxf(n, 1e-8f);
  return make_float3(v.x*inv, v.y*inv, v.z*inv);
}
__device__ __forceinline__ float3 f3cross(float3 a, float3 b){
  return make_float3(a.y*b.z - a.z*b.y, a.z*b.x - a.x*b.z, a.x*b.y - a.y*b.x);
}
__device__ __forceinline__ float silu_f(float x){
  float ex = __expf(-x);
  return x * __builtin_amdgcn_rcpf(1.0f + ex);
}

// ---------- kernel 1: residue frames ----------
__global__ void frames_kernel(const float* __restrict__ pos, float* __restrict__ frames, int Nr){
  int n = blockIdx.x*blockDim.x + threadIdx.x;
  if (n >= Nr) return;
  int k = n - 1;
  if (k < 0) k = 0;
  int kmax = Nr - 3;
  if (k > kmax) k = kmax;
  float3 p0 = make_float3(pos[3*k+0], pos[3*k+1], pos[3*k+2]);
  float3 p1 = make_float3(pos[3*k+3], pos[3*k+4], pos[3*k+5]);
  float3 p2 = make_float3(pos[3*k+6], pos[3*k+7], pos[3*k+8]);
  float3 u0 = f3nrm(f3sub(p1,p0));
  float3 u1 = f3nrm(f3sub(p2,p1));
  float3 dif = f3nrm(f3sub(u0,u1));
  float3 cr  = f3nrm(f3cross(u0,u1));
  float3 vt  = f3nrm(f3cross(dif,cr));
  float* o = frames + (size_t)n*9;
  o[0]=dif.x; o[1]=dif.y; o[2]=dif.z;
  o[3]=cr.x;  o[4]=cr.y;  o[5]=cr.z;
  o[6]=vt.x;  o[7]=vt.y;  o[8]=vt.z;
}

// ---------- kernel 2: per-edge diff + proj ----------
__global__ void edgepre_kernel(const float* __restrict__ posl, const float* __restrict__ posr,
    const int* __restrict__ el, const int* __restrict__ er, const float* __restrict__ frames,
    float* __restrict__ ediff, float* __restrict__ proj, int E){
  int e = blockIdx.x*blockDim.x + threadIdx.x;
  if (e >= E) return;
  int a = el[e], r = er[e];
  float3 pa = make_float3(posl[3*a+0], posl[3*a+1], posl[3*a+2]);
  float3 pr = make_float3(posr[3*r+0], posr[3*r+1], posr[3*r+2]);
  float3 ed = f3nrm(f3sub(pa,pr));
  const float* F = frames + (size_t)r*9;
  float px = ed.x*F[0] + ed.y*F[3] + ed.z*F[6];
  float py = ed.x*F[1] + ed.y*F[4] + ed.z*F[7];
  float pz = ed.x*F[2] + ed.y*F[5] + ed.z*F[8];
  ediff[3*e+0]=ed.x; ediff[3*e+1]=ed.y; ediff[3*e+2]=ed.z;
  proj[3*e+0]=px; proj[3*e+1]=py; proj[3*e+2]=pz;
}

#define GT 64

// ---------- kernel 3a: dense pre-GEMM  ligL = lig@W1, resL = res@W1 ----------
__global__ __launch_bounds__(256) void pre_gemm_kernel(
    const float* __restrict__ lig, const float* __restrict__ res,
    const float* __restrict__ W,
    float* __restrict__ ligL, float* __restrict__ resL,
    int nBlkLig, int Nl, int Nr)
{
  __shared__ float sX[GT][132];
  __shared__ float sW[16][132];
  int b = blockIdx.x;
  const float* X; float* O; int row0, rows;
  if (b < nBlkLig){ X = lig; O = ligL; row0 = b*GT;            rows = Nl; }
  else            { X = res; O = resL; row0 = (b-nBlkLig)*GT;  rows = Nr; }
  int tid = threadIdx.x;

  {
    int r = tid >> 2, p = tid & 3, cb = p*32;
    int row = row0 + r;
    if (row < rows){
      const float* src = X + (size_t)row*128 + cb;
      #pragma unroll
      for (int i = 0; i < 32; i += 4) *(float4*)&sX[r][cb+i] = *(const float4*)(src+i);
    } else {
      float4 z = make_float4(0.f,0.f,0.f,0.f);
      #pragma unroll
      for (int i = 0; i < 32; i += 4) *(float4*)&sX[r][cb+i] = z;
    }
  }

  int rg = tid >> 4, cg = tid & 15;
  int r0 = rg*4, c0 = cg*8;
  float acc[4][8];
  for (int i=0;i<4;i++)
    for (int j=0;j<8;j++) acc[i][j]=0.f;

  for (int kc = 0; kc < 128; kc += 16) {
    __syncthreads();
    {
      int kk = tid >> 4, cc = (tid & 15)*8;
      const float* src = W + (size_t)(kc+kk)*128 + cc;
      *(float4*)&sW[kk][cc]   = *(const float4*)src;
      *(float4*)&sW[kk][cc+4] = *(const float4*)(src+4);
    }
    __syncthreads();
    #pragma unroll
    for (int k4 = 0; k4 < 16; k4 += 4) {
      float xr[4][4];
      #pragma unroll
      for (int i=0;i<4;i++){
        float4 t = *(const float4*)&sX[r0+i][kc+k4];
        xr[i][0]=t.x; xr[i][1]=t.y; xr[i][2]=t.z; xr[i][3]=t.w;
      }
      #pragma unroll
      for (int kk=0;kk<4;kk++){
        float4 w0 = *(const float4*)&sW[k4+kk][c0];
        float4 w1 = *(const float4*)&sW[k4+kk][c0+4];
        float wr[8] = {w0.x,w0.y,w0.z,w0.w,w1.x,w1.y,w1.z,w1.w};
        #pragma unroll
        for (int i=0;i<4;i++){
          #pragma unroll
          for (int j=0;j<8;j++)
            acc[i][j] = fmaf(xr[i][kk], wr[j], acc[i][j]);
        }
      }
    }
  }

  #pragma unroll
  for (int i=0;i<4;i++){
    int row = row0 + r0 + i;
    if (row < rows){
      *(float4*)(O + (size_t)row*128 + c0)     = make_float4(acc[i][0],acc[i][1],acc[i][2],acc[i][3]);
      *(float4*)(O + (size_t)row*128 + c0 + 4) = make_float4(acc[i][4],acc[i][5],acc[i][6],acc[i][7]);
    }
  }
}

// ---------- kernel 3b: h = silu(ligL[el]+resL[er]+b1) @ W2 + b2 -> bf16 ----------
__global__ __launch_bounds__(256) void h_gemm2_kernel(
    const float* __restrict__ ligL, const float* __restrict__ resL,
    const int* __restrict__ el, const int* __restrict__ er,
    const float* __restrict__ b1,
    const float* __restrict__ W2, const float* __restrict__ b2,
    __hip_bfloat16* __restrict__ hout, int E)
{
  __shared__ float sY[GT][132];
  __shared__ float sW[16][132];
  int tid = threadIdx.x;
  int e0 = blockIdx.x * GT;

  {
    int r = tid >> 2, p = tid & 3, cb = p*32;
    int e = e0 + r;
    if (e < E){
      const float* la = ligL + (size_t)el[e]*128 + cb;
      const float* ra = resL + (size_t)er[e]*128 + cb;
      #pragma unroll
      for (int i = 0; i < 32; i += 4){
        float4 va = *(const float4*)(la+i);
        float4 vb = *(const float4*)(ra+i);
        float4 bb = *(const float4*)(b1+cb+i);
        va.x = silu_f(va.x+vb.x+bb.x);
        va.y = silu_f(va.y+vb.y+bb.y);
        va.z = silu_f(va.z+vb.z+bb.z);
        va.w = silu_f(va.w+vb.w+bb.w);
        *(float4*)&sY[r][cb+i] = va;
      }
    } else {
      float4 z = make_float4(0.f,0.f,0.f,0.f);
      #pragma unroll
      for (int i = 0; i < 32; i += 4) *(float4*)&sY[r][cb+i] = z;
    }
  }

  int rg = tid >> 4, cg = tid & 15;
  int r0 = rg*4, c0 = cg*8;
  float acc[4][8];
  for (int i=0;i<4;i++)
    for (int j=0;j<8;j++) acc[i][j]=0.f;

  for (int kc = 0; kc < 128; kc += 16) {
    __syncthreads();
    {
      int kk = tid >> 4, cc = (tid & 15)*8;
      const float* src = W2 + (size_t)(kc+kk)*128 + cc;
      *(float4*)&sW[kk][cc]   = *(const float4*)src;
      *(float4*)&sW[kk][cc+4] = *(const float4*)(src+4);
    }
    __syncthreads();
    #pragma unroll
    for (int k4 = 0; k4 < 16; k4 += 4) {
      float xr[4][4];
      #pragma unroll
      for (int i=0;i<4;i++){
        float4 t = *(const float4*)&sY[r0+i][kc+k4];
        xr[i][0]=t.x; xr[i][1]=t.y; xr[i][2]=t.z; xr[i][3]=t.w;
      }
      #pragma unroll
      for (int kk=0;kk<4;kk++){
        float4 w0 = *(const float4*)&sW[k4+kk][c0];
        float4 w1 = *(const float4*)&sW[k4+kk][c0+4];
        float wr[8] = {w0.x,w0.y,w0.z,w0.w,w1.x,w1.y,w1.z,w1.w};
        #pragma unroll
        for (int i=0;i<4;i++){
          #pragma unroll
          for (int j=0;j<8;j++)
            acc[i][j] = fmaf(xr[i][kk], wr[j], acc[i][j]);
        }
      }
    }
  }

  {
    float bj[8];
    #pragma unroll
    for (int j=0;j<8;j++) bj[j] = b2[c0+j];
    #pragma unroll
    for (int i=0;i<4;i++){
      int e = e0 + r0 + i;
      if (e < E){
        union { __hip_bfloat16 b[8]; uint4 u; } cv;
        #pragma unroll
        for (int j=0;j<8;j++) cv.b[j] = __float2bfloat16(acc[i][j]+bj[j]);
        *(uint4*)(hout + (size_t)e*128 + c0) = cv.u;
      }
    }
  }
}

// ---------- kernel 4a: per-edge Hermite spline of f(h)=sum_q silu(h*A_q+b_q)*w_q ----------
// 8 edges/block, NIV=15 intervals (16 nodes): phase 2 = exactly 256 tasks.
#define EPB 8
#define NIV 15
__global__ __launch_bounds__(256) void edgew_kernel(
    const __hip_bfloat16* __restrict__ hbuf, const float* __restrict__ proj,
    const float* __restrict__ Wa1, const float* __restrict__ ba1,
    const float* __restrict__ Wb1, const float* __restrict__ bb1,
    const float* __restrict__ Wa2, const float* __restrict__ ba2,
    const float* __restrict__ Wb2, const float* __restrict__ bb2,
    __hip_bfloat16* __restrict__ w01, __hip_bfloat16* __restrict__ w02, int E)
{
  __shared__ float sA[2][EPB][32];
  __shared__ float sBA[2][32], sWB[2][32];
  __shared__ float sNF[EPB][2][NIV+1], sND[EPB][2][NIV+1];
  __shared__ float4 sCo[EPB][2][NIV];
  __shared__ float sMin[EPB], sMax[EPB];
  __shared__ float sH0[EPB], sInvD[EPB], sDv[EPB], sP0[EPB];

  int tid = threadIdx.x;
  int ee  = tid >> 5;            // edge slot (phase 1/3): one 32-lane group per edge
  int lg  = tid & 31;
  int e   = blockIdx.x*EPB + ee; if (e >= E) e = E-1;
  int d0  = lg*4;

  // P1: load 4 h values (bf16x4), group min/max
  union { ushort4 u; __hip_bfloat16 b[4]; } HU;
  HU.u = *reinterpret_cast<const ushort4*>(hbuf + (size_t)e*128 + d0);
  float hv0 = __bfloat162float(HU.b[0]);
  float hv1 = __bfloat162float(HU.b[1]);
  float hv2 = __bfloat162float(HU.b[2]);
  float hv3 = __bfloat162float(HU.b[3]);
  float mn = fminf(fminf(hv0,hv1), fminf(hv2,hv3));
  float mx = fmaxf(fmaxf(hv0,hv1), fmaxf(hv2,hv3));
  #pragma unroll
  for (int o = 16; o > 0; o >>= 1){
    mn = fminf(mn, __shfl_xor(mn, o));
    mx = fmaxf(mx, __shfl_xor(mx, o));
  }
  if (lg == 0){ sMin[ee] = mn; sMax[ee] = mx; }
  if (tid < 64){
    int br = tid>>5, q = tid&31;
    sBA[br][q] = br ? ba2[q] : ba1[q];
    sWB[br][q] = br ? Wb2[q] : Wb1[q];
  }
  __syncthreads();

  // P1b: per-edge A_q (512 tasks) + per-edge scalars
  for (int t = tid; t < 512; t += 256){
    int ee2 = t>>6, rem = t&63, br = rem>>5, q = rem&31;
    int e2 = blockIdx.x*EPB + ee2; if (e2 >= E) e2 = E-1;
    const float* Wa = br ? Wa2 : Wa1;
    float p0 = proj[3*e2+0], p1 = proj[3*e2+1], p2 = proj[3*e2+2];
    sA[br][ee2][q] = p0*Wa[q] + p1*Wa[32+q] + p2*Wa[64+q];
  }
  if (tid < EPB){
    int e3 = blockIdx.x*EPB + tid; if (e3 >= E) e3 = E-1;
    float range = fmaxf(sMax[tid]-sMin[tid], 1e-3f);
    float Dv = range * (1.0f/NIV);
    sH0[tid]   = sMin[tid];
    sDv[tid]   = Dv;
    sInvD[tid] = (float)NIV / range;
    sP0[tid]   = proj[3*e3];
  }
  __syncthreads();

  // P2: exact f,f' at 16 nodes — exactly one (edge,branch,node) per thread
  {
    int ee2 = tid>>5, br = (tid>>4)&1, node = tid&15;
    float hh0 = sH0[ee2], Dv = sDv[ee2];
    float hn = fmaf((float)node, Dv, hh0);
    float f = 0.f, fd = 0.f;
    #pragma unroll 8
    for (int q = 0; q < 32; ++q){
      float a = sA[br][ee2][q], b = sBA[br][q], w = sWB[br][q];
      float x  = fmaf(hn, a, b);
      float ex = __expf(-x);
      float sg = __builtin_amdgcn_rcpf(1.0f + ex);     // sigmoid
      f  = fmaf(w, x*sg, f);                            // + w*silu
      float sp = sg * fmaf(x, 1.0f - sg, 1.0f);         // silu'
      fd = fmaf(w*a, sp, fd);
    }
    sNF[ee2][br][node] = f;
    sND[ee2][br][node] = fd;
  }
  __syncthreads();

  // P2.5: Hermite cubic coeffs (240 active of 256)
  {
    int ee2 = tid>>5, rem = tid&31, br = rem>>4, i = rem&15;
    if (i < NIV){
      float Dv = sDv[ee2];
      float f0 = sNF[ee2][br][i],    f1 = sNF[ee2][br][i+1];
      float g0 = sND[ee2][br][i]*Dv, g1 = sND[ee2][br][i+1]*Dv;
      float bb = br ? bb2[0] : bb1[0];
      float df = f1 - f0;
      sCo[ee2][br][i] = make_float4(f0+bb, g0, 3.f*df-2.f*g0-g1, g0+g1-2.f*df);
    }
  }
  __syncthreads();

  // P3: evaluate 4 h's x 2 branches, pack bf16x4
  {
    float hh0 = sH0[ee], invD = sInvD[ee], p0v = sP0[ee];
    float hv[4] = {hv0,hv1,hv2,hv3};
    union { __hip_bfloat16 b[4]; uint2 u; } O1, O2;
    #pragma unroll
    for (int k = 0; k < 4; ++k){
      float sf = (hv[k]-hh0)*invD;
      int ii = (int)floorf(sf);
      ii = ii < 0 ? 0 : (ii > NIV-1 ? NIV-1 : ii);
      float s = sf - (float)ii;
      float4 C1 = sCo[ee][0][ii];
      float4 C2 = sCo[ee][1][ii];
      float hp = hv[k]*p0v;
      O1.b[k] = __float2bfloat16(fmaf(fmaf(fmaf(C1.w,s,C1.z),s,C1.y),s,C1.x) + hp);
      O2.b[k] = __float2bfloat16(fmaf(fmaf(fmaf(C2.w,s,C2.z),s,C2.y),s,C2.x) + hp);
    }
    *reinterpret_cast<uint2*>(w01 + (size_t)e*128 + d0) = O1.u;
    *reinterpret_cast<uint2*>(w02 + (size_t)e*128 + d0) = O2.u;
  }
}

// ---------- kernel 4b: per-atom segmented reduce + lv update ----------
__global__ __launch_bounds__(128) void reduce_kernel(
    const __hip_bfloat16* __restrict__ w01, const __hip_bfloat16* __restrict__ w02,
    const float* __restrict__ ediff, const int* __restrict__ el,
    float* __restrict__ lv, int E, int layer)
{
  int a = blockIdx.x;
  int d = threadIdx.x;

  int lo = 0, hi = E;
  while (lo < hi){ int m = (lo+hi)>>1; if (el[m] < a) lo = m+1; else hi = m; }
  int estart = lo;
  int lo2 = lo, hi2 = E;
  while (lo2 < hi2){ int m = (lo2+hi2)>>1; if (el[m] <= a) lo2 = m+1; else hi2 = m; }
  int eend = lo2;

  float sumw = 0.f, tx = 0.f, ty = 0.f, tz = 0.f;
  for (int e = estart; e < eend; ++e){
    float w1 = __bfloat162float(w01[(size_t)e*128 + d]);
    float w2 = __bfloat162float(w02[(size_t)e*128 + d]);
    float ex = ediff[3*e+0], ey = ediff[3*e+1], ez = ediff[3*e+2];
    sumw += w1;
    tx = fmaf(ex, w2, tx);
    ty = fmaf(ey, w2, ty);
    tz = fmaf(ez, w2, tz);
  }

  size_t base = (size_t)a*384 + d;
  if (layer == 0){
    lv[base      ] = tx;
    lv[base + 128] = ty;
    lv[base + 256] = tz;
  } else {
    float m = 1.0f + sumw;
    lv[base      ] = lv[base      ]*m + tx;
    lv[base + 128] = lv[base + 128]*m + ty;
    lv[base + 256] = lv[base + 256]*m + tz;
  }
}

// ---------- kernel 5: head ----------
__global__ __launch_bounds__(128) void head_kernel(
    const float* __restrict__ lv, const float* __restrict__ Wl1, const float* __restrict__ bl1,
    const float* __restrict__ Wl2, const float* __restrict__ bl2,
    const float* __restrict__ lvin, float* __restrict__ out, int Nl)
{
  int a = blockIdx.x, d = threadIdx.x;
  __shared__ float slv[3][128];
  __shared__ float sred[2][3];
  size_t base = (size_t)a*384;
  slv[0][d] = lv[base + d];
  slv[1][d] = lv[base + 128 + d];
  slv[2][d] = lv[base + 256 + d];
  __syncthreads();
  float b = bl1[d];
  float a0 = b, a1 = b, a2 = b;
  #pragma unroll 4
  for (int k = 0; k < 128; ++k) {
    float w = Wl1[k*128 + d];
    a0 = fmaf(slv[0][k], w, a0);
    a1 = fmaf(slv[1][k], w, a1);
    a2 = fmaf(slv[2][k], w, a2);
  }
  float wl2 = Wl2[d];
  float z0 = fmaxf(a0, 0.f)*wl2;
  float z1 = fmaxf(a1, 0.f)*wl2;
  float z2 = fmaxf(a2, 0.f)*wl2;
  #pragma unroll
  for (int off = 32; off > 0; off >>= 1) {
    z0 += __shfl_down(z0, off);
    z1 += __shfl_down(z1, off);
    z2 += __shfl_down(z2, off);
  }
  int wv = d >> 6;
  if ((d & 63) == 0) { sred[wv][0]=z0; sred[wv][1]=z1; sred[wv][2]=z2; }
  __syncthreads();
  if (d == 0) {
    float bb = bl2[0];
    out[a*3+0] = sred[0][0]+sred[1][0] + bb + lvin[a*3+0];
    out[a*3+1] = sred[0][1]+sred[1][1] + bb + lvin[a*3+1];
    out[a*3+2] = sred[0][2]+sred[1][2] + bb + lvin[a*3+2];
  }
}

// ---------- launcher ----------
extern "C" void kernel_launch(void* const* d_in, const int* in_sizes, int n_in,
                              void* d_out, int out_size, void* d_ws, size_t ws_size,
                              hipStream_t stream)
{
  const float* lig   = (const float*)d_in[0];
  const float* lvin  = (const float*)d_in[1];
  const float* posl  = (const float*)d_in[2];
  const float* res   = (const float*)d_in[3];
  const float* posr  = (const float*)d_in[4];
  const int*   el    = (const int*)d_in[7];
  const int*   er    = (const int*)d_in[8];
  const float* Win1  = (const float*)d_in[9];
  const float* bin1  = (const float*)d_in[10];
  const float* Win2  = (const float*)d_in[11];
  const float* bin2  = (const float*)d_in[12];
  const float* Ws1a  = (const float*)d_in[13];
  const float* bs1a  = (const float*)d_in[14];
  const float* Ws1b  = (const float*)d_in[15];
  const float* bs1b  = (const float*)d_in[16];
  const float* Ws2a  = (const float*)d_in[17];
  const float* bs2a  = (const float*)d_in[18];
  const float* Ws2b  = (const float*)d_in[19];
  const float* bs2b  = (const float*)d_in[20];
  const float* Wl1   = (const float*)d_in[21];
  const float* bl1   = (const float*)d_in[22];
  const float* Wl2   = (const float*)d_in[23];
  const float* bl2   = (const float*)d_in[24];

  int Nl = in_sizes[2] / 3;
  int Nr = in_sizes[4] / 3;
  int E  = in_sizes[7];

  char* wsb = (char*)d_ws;
  size_t off = 0;
  auto carve = [&](size_t bytes) -> char* {
    char* p = wsb + off;
    off += (bytes + 255) & ~(size_t)255;
    return p;
  };
  float* frames = (float*)carve((size_t)Nr*9*4);
  float* ediff  = (float*)carve((size_t)E*3*4);
  float* proj   = (float*)carve((size_t)E*3*4);
  __hip_bfloat16* hbuf = (__hip_bfloat16*)carve((size_t)E*128*2);
  __hip_bfloat16* w01  = (__hip_bfloat16*)carve((size_t)E*128*2);
  __hip_bfloat16* w02  = (__hip_bfloat16*)carve((size_t)E*128*2);
  float* lvbuf  = (float*)carve((size_t)Nl*384*4);
  float* ligL   = (float*)carve((size_t)Nl*128*4);
  float* resL   = (float*)carve((size_t)Nr*128*4);

  int nBlkLig = (Nl + GT - 1)/GT;
  int nBlkRes = (Nr + GT - 1)/GT;

  hipLaunchKernelGGL(frames_kernel, dim3((Nr+255)/256), dim3(256), 0, stream, posr, frames, Nr);
  hipLaunchKernelGGL(edgepre_kernel, dim3((E+255)/256), dim3(256), 0, stream,
                     posl, posr, el, er, frames, ediff, proj, E);
  for (int l = 0; l < 2; ++l) {
    hipLaunchKernelGGL(pre_gemm_kernel, dim3(nBlkLig+nBlkRes), dim3(256), 0, stream,
        lig, res, Win1 + (size_t)l*16384, ligL, resL, nBlkLig, Nl, Nr);
    hipLaunchKernelGGL(h_gemm2_kernel, dim3((E+GT-1)/GT), dim3(256), 0, stream,
        ligL, resL, el, er,
        bin1 + (size_t)l*128,
        Win2 + (size_t)l*16384, bin2 + (size_t)l*128,
        hbuf, E);
    hipLaunchKernelGGL(edgew_kernel, dim3((E+EPB-1)/EPB), dim3(256), 0, stream,
        hbuf, proj,
        Ws1a + (size_t)l*96, bs1a + (size_t)l*32, Ws1b + (size_t)l*32, bs1b + l,
        Ws2a + (size_t)l*96, bs2a + (size_t)l*32, Ws2b + (size_t)l*32, bs2b + l,
        w01, w02, E);
    hipLaunchKernelGGL(reduce_kernel, dim3(Nl), dim3(128), 0, stream,
        w01, w02, ediff, el, lvbuf, E, l);
  }
  hipLaunchKernelGGL(head_kernel, dim3(Nl), dim3(128), 0, stream,
                     lvbuf, Wl1, bl1, Wl2, bl2, lvin, (float*)d_out, Nl);
}

// Round 6
// 299.720 us; speedup vs baseline: 6.8961x; 1.4545x over previous
//
#include <hip/hip_runtime.h>
#include <hip/hip_bf16.h>
#include <math.h>

typedef short bf16x8 __attribute__((ext_vector_type(8)));
typedef float f32x4 __attribute__((ext_vector_type(4)));

union BU8 { uint4 u; __hip_bfloat16 h[8]; ushort s[8]; };

// ---------- small helpers ----------
__device__ __forceinline__ float3 f3sub(float3 a, float3 b){ return make_float3(a.x-b.x, a.y-b.y, a.z-b.z); }
__device__ __forceinline__ float3 f3nrm(float3 v){
  float n = sqrtf(v.x*v.x + v.y*v.y + v.z*v.z);
  float inv = 1.0f / fmaxf(n, 1e-8f);
  return make_float3(v.x*inv, v.y*inv, v.z*inv);
}
__device__ __forceinline__ float3 f3cross(float3 a, float3 b){
  return make_float3(a.y*b.z - a.z*b.y, a.z*b.x - a.x*b.z, a.x*b.y - a.y*b.x);
}
__device__ __forceinline__ float silu_f(float x){
  float ex = __expf(-x);
  return x * __builtin_amdgcn_rcpf(1.0f + ex);
}

// ---------- kernel 1: residue frames ----------
__global__ void frames_kernel(const float* __restrict__ pos, float* __restrict__ frames, int Nr){
  int n = blockIdx.x*blockDim.x + threadIdx.x;
  if (n >= Nr) return;
  int k = n - 1;
  if (k < 0) k = 0;
  int kmax = Nr - 3;
  if (k > kmax) k = kmax;
  float3 p0 = make_float3(pos[3*k+0], pos[3*k+1], pos[3*k+2]);
  float3 p1 = make_float3(pos[3*k+3], pos[3*k+4], pos[3*k+5]);
  float3 p2 = make_float3(pos[3*k+6], pos[3*k+7], pos[3*k+8]);
  float3 u0 = f3nrm(f3sub(p1,p0));
  float3 u1 = f3nrm(f3sub(p2,p1));
  float3 dif = f3nrm(f3sub(u0,u1));
  float3 cr  = f3nrm(f3cross(u0,u1));
  float3 vt  = f3nrm(f3cross(dif,cr));
  float* o = frames + (size_t)n*9;
  o[0]=dif.x; o[1]=dif.y; o[2]=dif.z;
  o[3]=cr.x;  o[4]=cr.y;  o[5]=cr.z;
  o[6]=vt.x;  o[7]=vt.y;  o[8]=vt.z;
}

// ---------- kernel 2: per-edge diff + proj ----------
__global__ void edgepre_kernel(const float* __restrict__ posl, const float* __restrict__ posr,
    const int* __restrict__ el, const int* __restrict__ er, const float* __restrict__ frames,
    float* __restrict__ ediff, float* __restrict__ proj, int E){
  int e = blockIdx.x*blockDim.x + threadIdx.x;
  if (e >= E) return;
  int a = el[e], r = er[e];
  float3 pa = make_float3(posl[3*a+0], posl[3*a+1], posl[3*a+2]);
  float3 pr = make_float3(posr[3*r+0], posr[3*r+1], posr[3*r+2]);
  float3 ed = f3nrm(f3sub(pa,pr));
  const float* F = frames + (size_t)r*9;
  float px = ed.x*F[0] + ed.y*F[3] + ed.z*F[6];
  float py = ed.x*F[1] + ed.y*F[4] + ed.z*F[7];
  float pz = ed.x*F[2] + ed.y*F[5] + ed.z*F[8];
  ediff[3*e+0]=ed.x; ediff[3*e+1]=ed.y; ediff[3*e+2]=ed.z;
  proj[3*e+0]=px; proj[3*e+1]=py; proj[3*e+2]=pz;
}

// ---------- kernel W: transpose+convert weights: Wt[l][n][k] = bf16(W[l][k][n]) ----------
__global__ void wprep_kernel(const float* __restrict__ W, __hip_bfloat16* __restrict__ Wt, int total){
  int idx = blockIdx.x*blockDim.x + threadIdx.x;
  if (idx >= total) return;
  int l = idx >> 14, rem = idx & 16383, n = rem >> 7, k = rem & 127;
  Wt[idx] = __float2bfloat16(W[(l<<14) + (k<<7) + n]);
}

// ---------- kernel 3a: MFMA pre-GEMM  ligLb = bf16(lig)@W1t^T, resLb likewise ----------
// block: 64 rows x 128 cols, 4 waves; wave: all 64 rows x 32 cols.
__global__ __launch_bounds__(256) void pre_gemm_mfma(
    const float* __restrict__ lig, const float* __restrict__ res,
    const __hip_bfloat16* __restrict__ W1t,
    __hip_bfloat16* __restrict__ ligLb, __hip_bfloat16* __restrict__ resLb,
    int nBlkLig, int Nl, int Nr)
{
  __shared__ __hip_bfloat16 sA[64][136];
  __shared__ __hip_bfloat16 sB[128][136];
  int b = blockIdx.x;
  const float* X; __hip_bfloat16* O; int row0, rows;
  if (b < nBlkLig){ X = lig; O = ligLb; row0 = b*64;            rows = Nl; }
  else            { X = res; O = resLb; row0 = (b-nBlkLig)*64;  rows = Nr; }
  int tid = threadIdx.x;

  // stage sB = W1t rows (n-major, k-contig)
  {
    int n = tid >> 1, c0 = (tid & 1) * 64;
    const ushort* src = (const ushort*)W1t + n*128 + c0;
    ushort* dst = (ushort*)&sB[n][0] + c0;
    #pragma unroll
    for (int i = 0; i < 64; i += 8) *(uint4*)(dst + i) = *(const uint4*)(src + i);
  }
  // stage sA = bf16(X rows)
  {
    int r = tid >> 2, p = tid & 3, cb = p*32;
    int row = row0 + r; if (row >= rows) row = rows - 1;
    const float* src = X + (size_t)row*128 + cb;
    ushort* dst = (ushort*)&sA[r][0] + cb;
    #pragma unroll
    for (int i = 0; i < 32; i += 8){
      float4 v0 = *(const float4*)(src + i);
      float4 v1 = *(const float4*)(src + i + 4);
      BU8 o;
      o.h[0]=__float2bfloat16(v0.x); o.h[1]=__float2bfloat16(v0.y);
      o.h[2]=__float2bfloat16(v0.z); o.h[3]=__float2bfloat16(v0.w);
      o.h[4]=__float2bfloat16(v1.x); o.h[5]=__float2bfloat16(v1.y);
      o.h[6]=__float2bfloat16(v1.z); o.h[7]=__float2bfloat16(v1.w);
      *(uint4*)(dst + i) = o.u;
    }
  }
  __syncthreads();

  int w = tid >> 6, l = tid & 63;
  int lrow = l & 15, lko = (l >> 4) * 8;
  f32x4 acc[4][2];
  for (int mt=0; mt<4; ++mt)
    for (int nt=0; nt<2; ++nt)
      acc[mt][nt] = (f32x4){0.f,0.f,0.f,0.f};

  #pragma unroll
  for (int kc = 0; kc < 128; kc += 32){
    bf16x8 af[4], bfr[2];
    #pragma unroll
    for (int mt=0; mt<4; ++mt)
      af[mt] = *(const bf16x8*)((const ushort*)&sA[0][0] + (mt*16+lrow)*136 + kc + lko);
    #pragma unroll
    for (int nt=0; nt<2; ++nt)
      bfr[nt] = *(const bf16x8*)((const ushort*)&sB[0][0] + (w*32+nt*16+lrow)*136 + kc + lko);
    #pragma unroll
    for (int mt=0; mt<4; ++mt){
      #pragma unroll
      for (int nt=0; nt<2; ++nt)
        acc[mt][nt] = __builtin_amdgcn_mfma_f32_16x16x32_bf16(af[mt], bfr[nt], acc[mt][nt], 0, 0, 0);
    }
  }

  // epilogue: O[row][n] = bf16(acc)
  int orow = (l >> 4) * 4;
  #pragma unroll
  for (int mt=0; mt<4; ++mt){
    #pragma unroll
    for (int nt=0; nt<2; ++nt){
      int n = w*32 + nt*16 + (l & 15);
      #pragma unroll
      for (int j=0; j<4; ++j){
        int row = row0 + mt*16 + orow + j;
        if (row < rows) O[(size_t)row*128 + n] = __float2bfloat16(acc[mt][nt][j]);
      }
    }
  }
}

// ---------- kernel 3b: h = silu(ligLb[el]+resLb[er]+b1) @ W2 + b2 -> bf16 (MFMA) ----------
__global__ __launch_bounds__(256) void h_gemm2_mfma(
    const __hip_bfloat16* __restrict__ ligLb, const __hip_bfloat16* __restrict__ resLb,
    const int* __restrict__ el, const int* __restrict__ er,
    const float* __restrict__ b1,
    const __hip_bfloat16* __restrict__ W2t, const float* __restrict__ b2,
    __hip_bfloat16* __restrict__ hout, int E)
{
  __shared__ __hip_bfloat16 sA[64][136];
  __shared__ __hip_bfloat16 sB[128][136];
  int tid = threadIdx.x;
  int e0 = blockIdx.x * 64;

  // stage sB = W2t
  {
    int n = tid >> 1, c0 = (tid & 1) * 64;
    const ushort* src = (const ushort*)W2t + n*128 + c0;
    ushort* dst = (ushort*)&sB[n][0] + c0;
    #pragma unroll
    for (int i = 0; i < 64; i += 8) *(uint4*)(dst + i) = *(const uint4*)(src + i);
  }
  // stage sA = bf16(silu(ligLb[el]+resLb[er]+b1))
  {
    int r = tid >> 2, p = tid & 3, cb = p*32;
    int e = e0 + r; if (e >= E) e = E - 1;
    const ushort* la = (const ushort*)ligLb + (size_t)el[e]*128 + cb;
    const ushort* ra = (const ushort*)resLb + (size_t)er[e]*128 + cb;
    ushort* dst = (ushort*)&sA[r][0] + cb;
    #pragma unroll
    for (int i = 0; i < 32; i += 8){
      BU8 A, B, O;
      A.u = *(const uint4*)(la + i);
      B.u = *(const uint4*)(ra + i);
      float4 bb0 = *(const float4*)(b1 + cb + i);
      float4 bb1 = *(const float4*)(b1 + cb + i + 4);
      float bbs[8] = {bb0.x,bb0.y,bb0.z,bb0.w,bb1.x,bb1.y,bb1.z,bb1.w};
      #pragma unroll
      for (int j=0; j<8; ++j){
        float x = __bfloat162float(A.h[j]) + __bfloat162float(B.h[j]) + bbs[j];
        O.h[j] = __float2bfloat16(silu_f(x));
      }
      *(uint4*)(dst + i) = O.u;
    }
  }
  __syncthreads();

  int w = tid >> 6, l = tid & 63;
  int lrow = l & 15, lko = (l >> 4) * 8;
  f32x4 acc[4][2];
  for (int mt=0; mt<4; ++mt)
    for (int nt=0; nt<2; ++nt)
      acc[mt][nt] = (f32x4){0.f,0.f,0.f,0.f};

  #pragma unroll
  for (int kc = 0; kc < 128; kc += 32){
    bf16x8 af[4], bfr[2];
    #pragma unroll
    for (int mt=0; mt<4; ++mt)
      af[mt] = *(const bf16x8*)((const ushort*)&sA[0][0] + (mt*16+lrow)*136 + kc + lko);
    #pragma unroll
    for (int nt=0; nt<2; ++nt)
      bfr[nt] = *(const bf16x8*)((const ushort*)&sB[0][0] + (w*32+nt*16+lrow)*136 + kc + lko);
    #pragma unroll
    for (int mt=0; mt<4; ++mt){
      #pragma unroll
      for (int nt=0; nt<2; ++nt)
        acc[mt][nt] = __builtin_amdgcn_mfma_f32_16x16x32_bf16(af[mt], bfr[nt], acc[mt][nt], 0, 0, 0);
    }
  }

  int orow = (l >> 4) * 4;
  #pragma unroll
  for (int mt=0; mt<4; ++mt){
    #pragma unroll
    for (int nt=0; nt<2; ++nt){
      int n = w*32 + nt*16 + (l & 15);
      float bb = b2[n];
      #pragma unroll
      for (int j=0; j<4; ++j){
        int e = e0 + mt*16 + orow + j;
        if (e < E) hout[(size_t)e*128 + n] = __float2bfloat16(acc[mt][nt][j] + bb);
      }
    }
  }
}

// ---------- kernel 4a: per-edge Hermite spline of f(h)=sum_q silu(h*A_q+b_q)*w_q ----------
#define EPB 8
#define NIV 15
__global__ __launch_bounds__(256) void edgew_kernel(
    const __hip_bfloat16* __restrict__ hbuf, const float* __restrict__ proj,
    const float* __restrict__ Wa1, const float* __restrict__ ba1,
    const float* __restrict__ Wb1, const float* __restrict__ bb1,
    const float* __restrict__ Wa2, const float* __restrict__ ba2,
    const float* __restrict__ Wb2, const float* __restrict__ bb2,
    __hip_bfloat16* __restrict__ w01, __hip_bfloat16* __restrict__ w02, int E)
{
  __shared__ float sA[2][EPB][32];
  __shared__ float sBA[2][32], sWB[2][32];
  __shared__ float sNF[EPB][2][NIV+1], sND[EPB][2][NIV+1];
  __shared__ float4 sCo[EPB][2][NIV];
  __shared__ float sMin[EPB], sMax[EPB];
  __shared__ float sH0[EPB], sInvD[EPB], sDv[EPB], sP0[EPB];

  int tid = threadIdx.x;
  int ee  = tid >> 5;
  int lg  = tid & 31;
  int e   = blockIdx.x*EPB + ee; if (e >= E) e = E-1;
  int d0  = lg*4;

  union { ushort4 u; __hip_bfloat16 b[4]; } HU;
  HU.u = *reinterpret_cast<const ushort4*>(hbuf + (size_t)e*128 + d0);
  float hv0 = __bfloat162float(HU.b[0]);
  float hv1 = __bfloat162float(HU.b[1]);
  float hv2 = __bfloat162float(HU.b[2]);
  float hv3 = __bfloat162float(HU.b[3]);
  float mn = fminf(fminf(hv0,hv1), fminf(hv2,hv3));
  float mx = fmaxf(fmaxf(hv0,hv1), fmaxf(hv2,hv3));
  #pragma unroll
  for (int o = 16; o > 0; o >>= 1){
    mn = fminf(mn, __shfl_xor(mn, o));
    mx = fmaxf(mx, __shfl_xor(mx, o));
  }
  if (lg == 0){ sMin[ee] = mn; sMax[ee] = mx; }
  if (tid < 64){
    int br = tid>>5, q = tid&31;
    sBA[br][q] = br ? ba2[q] : ba1[q];
    sWB[br][q] = br ? Wb2[q] : Wb1[q];
  }
  __syncthreads();

  for (int t = tid; t < 512; t += 256){
    int ee2 = t>>6, rem = t&63, br = rem>>5, q = rem&31;
    int e2 = blockIdx.x*EPB + ee2; if (e2 >= E) e2 = E-1;
    const float* Wa = br ? Wa2 : Wa1;
    float p0 = proj[3*e2+0], p1 = proj[3*e2+1], p2 = proj[3*e2+2];
    sA[br][ee2][q] = p0*Wa[q] + p1*Wa[32+q] + p2*Wa[64+q];
  }
  if (tid < EPB){
    int e3 = blockIdx.x*EPB + tid; if (e3 >= E) e3 = E-1;
    float range = fmaxf(sMax[tid]-sMin[tid], 1e-3f);
    float Dv = range * (1.0f/NIV);
    sH0[tid]   = sMin[tid];
    sDv[tid]   = Dv;
    sInvD[tid] = (float)NIV / range;
    sP0[tid]   = proj[3*e3];
  }
  __syncthreads();

  {
    int ee2 = tid>>5, br = (tid>>4)&1, node = tid&15;
    float hh0 = sH0[ee2], Dv = sDv[ee2];
    float hn = fmaf((float)node, Dv, hh0);
    float f = 0.f, fd = 0.f;
    #pragma unroll 8
    for (int q = 0; q < 32; ++q){
      float a = sA[br][ee2][q], b = sBA[br][q], w = sWB[br][q];
      float x  = fmaf(hn, a, b);
      float ex = __expf(-x);
      float sg = __builtin_amdgcn_rcpf(1.0f + ex);
      f  = fmaf(w, x*sg, f);
      float sp = sg * fmaf(x, 1.0f - sg, 1.0f);
      fd = fmaf(w*a, sp, fd);
    }
    sNF[ee2][br][node] = f;
    sND[ee2][br][node] = fd;
  }
  __syncthreads();

  {
    int ee2 = tid>>5, rem = tid&31, br = rem>>4, i = rem&15;
    if (i < NIV){
      float Dv = sDv[ee2];
      float f0 = sNF[ee2][br][i],    f1 = sNF[ee2][br][i+1];
      float g0 = sND[ee2][br][i]*Dv, g1 = sND[ee2][br][i+1]*Dv;
      float bb = br ? bb2[0] : bb1[0];
      float df = f1 - f0;
      sCo[ee2][br][i] = make_float4(f0+bb, g0, 3.f*df-2.f*g0-g1, g0+g1-2.f*df);
    }
  }
  __syncthreads();

  {
    float hh0 = sH0[ee], invD = sInvD[ee], p0v = sP0[ee];
    float hv[4] = {hv0,hv1,hv2,hv3};
    union { __hip_bfloat16 b[4]; uint2 u; } O1, O2;
    #pragma unroll
    for (int k = 0; k < 4; ++k){
      float sf = (hv[k]-hh0)*invD;
      int ii = (int)floorf(sf);
      ii = ii < 0 ? 0 : (ii > NIV-1 ? NIV-1 : ii);
      float s = sf - (float)ii;
      float4 C1 = sCo[ee][0][ii];
      float4 C2 = sCo[ee][1][ii];
      float hp = hv[k]*p0v;
      O1.b[k] = __float2bfloat16(fmaf(fmaf(fmaf(C1.w,s,C1.z),s,C1.y),s,C1.x) + hp);
      O2.b[k] = __float2bfloat16(fmaf(fmaf(fmaf(C2.w,s,C2.z),s,C2.y),s,C2.x) + hp);
    }
    *reinterpret_cast<uint2*>(w01 + (size_t)e*128 + d0) = O1.u;
    *reinterpret_cast<uint2*>(w02 + (size_t)e*128 + d0) = O2.u;
  }
}

// ---------- kernel 4b: per-atom segmented reduce + lv update ----------
__global__ __launch_bounds__(128) void reduce_kernel(
    const __hip_bfloat16* __restrict__ w01, const __hip_bfloat16* __restrict__ w02,
    const float* __restrict__ ediff, const int* __restrict__ el,
    float* __restrict__ lv, int E, int layer)
{
  int a = blockIdx.x;
  int d = threadIdx.x;

  int lo = 0, hi = E;
  while (lo < hi){ int m = (lo+hi)>>1; if (el[m] < a) lo = m+1; else hi = m; }
  int estart = lo;
  int lo2 = lo, hi2 = E;
  while (lo2 < hi2){ int m = (lo2+hi2)>>1; if (el[m] <= a) lo2 = m+1; else hi2 = m; }
  int eend = lo2;

  float sumw = 0.f, tx = 0.f, ty = 0.f, tz = 0.f;
  for (int e = estart; e < eend; ++e){
    float w1 = __bfloat162float(w01[(size_t)e*128 + d]);
    float w2 = __bfloat162float(w02[(size_t)e*128 + d]);
    float ex = ediff[3*e+0], ey = ediff[3*e+1], ez = ediff[3*e+2];
    sumw += w1;
    tx = fmaf(ex, w2, tx);
    ty = fmaf(ey, w2, ty);
    tz = fmaf(ez, w2, tz);
  }

  size_t base = (size_t)a*384 + d;
  if (layer == 0){
    lv[base      ] = tx;
    lv[base + 128] = ty;
    lv[base + 256] = tz;
  } else {
    float m = 1.0f + sumw;
    lv[base      ] = lv[base      ]*m + tx;
    lv[base + 128] = lv[base + 128]*m + ty;
    lv[base + 256] = lv[base + 256]*m + tz;
  }
}

// ---------- kernel 5: head ----------
__global__ __launch_bounds__(128) void head_kernel(
    const float* __restrict__ lv, const float* __restrict__ Wl1, const float* __restrict__ bl1,
    const float* __restrict__ Wl2, const float* __restrict__ bl2,
    const float* __restrict__ lvin, float* __restrict__ out, int Nl)
{
  int a = blockIdx.x, d = threadIdx.x;
  __shared__ float slv[3][128];
  __shared__ float sred[2][3];
  size_t base = (size_t)a*384;
  slv[0][d] = lv[base + d];
  slv[1][d] = lv[base + 128 + d];
  slv[2][d] = lv[base + 256 + d];
  __syncthreads();
  float b = bl1[d];
  float a0 = b, a1 = b, a2 = b;
  #pragma unroll 4
  for (int k = 0; k < 128; ++k) {
    float w = Wl1[k*128 + d];
    a0 = fmaf(slv[0][k], w, a0);
    a1 = fmaf(slv[1][k], w, a1);
    a2 = fmaf(slv[2][k], w, a2);
  }
  float wl2 = Wl2[d];
  float z0 = fmaxf(a0, 0.f)*wl2;
  float z1 = fmaxf(a1, 0.f)*wl2;
  float z2 = fmaxf(a2, 0.f)*wl2;
  #pragma unroll
  for (int off = 32; off > 0; off >>= 1) {
    z0 += __shfl_down(z0, off);
    z1 += __shfl_down(z1, off);
    z2 += __shfl_down(z2, off);
  }
  int wv = d >> 6;
  if ((d & 63) == 0) { sred[wv][0]=z0; sred[wv][1]=z1; sred[wv][2]=z2; }
  __syncthreads();
  if (d == 0) {
    float bb = bl2[0];
    out[a*3+0] = sred[0][0]+sred[1][0] + bb + lvin[a*3+0];
    out[a*3+1] = sred[0][1]+sred[1][1] + bb + lvin[a*3+1];
    out[a*3+2] = sred[0][2]+sred[1][2] + bb + lvin[a*3+2];
  }
}

// ---------- launcher ----------
extern "C" void kernel_launch(void* const* d_in, const int* in_sizes, int n_in,
                              void* d_out, int out_size, void* d_ws, size_t ws_size,
                              hipStream_t stream)
{
  const float* lig   = (const float*)d_in[0];
  const float* lvin  = (const float*)d_in[1];
  const float* posl  = (const float*)d_in[2];
  const float* res   = (const float*)d_in[3];
  const float* posr  = (const float*)d_in[4];
  const int*   el    = (const int*)d_in[7];
  const int*   er    = (const int*)d_in[8];
  const float* Win1  = (const float*)d_in[9];
  const float* bin1  = (const float*)d_in[10];
  const float* Win2  = (const float*)d_in[11];
  const float* bin2  = (const float*)d_in[12];
  const float* Ws1a  = (const float*)d_in[13];
  const float* bs1a  = (const float*)d_in[14];
  const float* Ws1b  = (const float*)d_in[15];
  const float* bs1b  = (const float*)d_in[16];
  const float* Ws2a  = (const float*)d_in[17];
  const float* bs2a  = (const float*)d_in[18];
  const float* Ws2b  = (const float*)d_in[19];
  const float* bs2b  = (const float*)d_in[20];
  const float* Wl1   = (const float*)d_in[21];
  const float* bl1   = (const float*)d_in[22];
  const float* Wl2   = (const float*)d_in[23];
  const float* bl2   = (const float*)d_in[24];

  int Nl = in_sizes[2] / 3;
  int Nr = in_sizes[4] / 3;
  int E  = in_sizes[7];

  char* wsb = (char*)d_ws;
  size_t off = 0;
  auto carve = [&](size_t bytes) -> char* {
    char* p = wsb + off;
    off += (bytes + 255) & ~(size_t)255;
    return p;
  };
  float* frames = (float*)carve((size_t)Nr*9*4);
  float* ediff  = (float*)carve((size_t)E*3*4);
  float* proj   = (float*)carve((size_t)E*3*4);
  __hip_bfloat16* hbuf  = (__hip_bfloat16*)carve((size_t)E*128*2);
  __hip_bfloat16* w01   = (__hip_bfloat16*)carve((size_t)E*128*2);
  __hip_bfloat16* w02   = (__hip_bfloat16*)carve((size_t)E*128*2);
  float* lvbuf  = (float*)carve((size_t)Nl*384*4);
  __hip_bfloat16* ligLb = (__hip_bfloat16*)carve((size_t)Nl*128*2);
  __hip_bfloat16* resLb = (__hip_bfloat16*)carve((size_t)Nr*128*2);
  __hip_bfloat16* W1t   = (__hip_bfloat16*)carve((size_t)2*16384*2);
  __hip_bfloat16* W2t   = (__hip_bfloat16*)carve((size_t)2*16384*2);

  int nBlkLig = (Nl + 63)/64;
  int nBlkRes = (Nr + 63)/64;

  hipLaunchKernelGGL(frames_kernel, dim3((Nr+255)/256), dim3(256), 0, stream, posr, frames, Nr);
  hipLaunchKernelGGL(edgepre_kernel, dim3((E+255)/256), dim3(256), 0, stream,
                     posl, posr, el, er, frames, ediff, proj, E);
  hipLaunchKernelGGL(wprep_kernel, dim3((2*16384+255)/256), dim3(256), 0, stream, Win1, W1t, 2*16384);
  hipLaunchKernelGGL(wprep_kernel, dim3((2*16384+255)/256), dim3(256), 0, stream, Win2, W2t, 2*16384);

  for (int l = 0; l < 2; ++l) {
    hipLaunchKernelGGL(pre_gemm_mfma, dim3(nBlkLig+nBlkRes), dim3(256), 0, stream,
        lig, res, W1t + (size_t)l*16384, ligLb, resLb, nBlkLig, Nl, Nr);
    hipLaunchKernelGGL(h_gemm2_mfma, dim3((E+63)/64), dim3(256), 0, stream,
        ligLb, resLb, el, er,
        bin1 + (size_t)l*128,
        W2t + (size_t)l*16384, bin2 + (size_t)l*128,
        hbuf, E);
    hipLaunchKernelGGL(edgew_kernel, dim3((E+EPB-1)/EPB), dim3(256), 0, stream,
        hbuf, proj,
        Ws1a + (size_t)l*96, bs1a + (size_t)l*32, Ws1b + (size_t)l*32, bs1b + l,
        Ws2a + (size_t)l*96, bs2a + (size_t)l*32, Ws2b + (size_t)l*32, bs2b + l,
        w01, w02, E);
    hipLaunchKernelGGL(reduce_kernel, dim3(Nl), dim3(128), 0, stream,
        w01, w02, ediff, el, lvbuf, E, l);
  }
  hipLaunchKernelGGL(head_kernel, dim3(Nl), dim3(128), 0, stream,
                     lvbuf, Wl1, bl1, Wl2, bl2, lvin, (float*)d_out, Nl);
}

// Round 7
// 296.819 us; speedup vs baseline: 6.9635x; 1.0098x over previous
//
#include <hip/hip_runtime.h>
#include <hip/hip_bf16.h>
#include <math.h>

typedef short bf16x8 __attribute__((ext_vector_type(8)));
typedef float f32x4 __attribute__((ext_vector_type(4)));

union BU8 { uint4 u; __hip_bfloat16 h[8]; ushort s[8]; };

// ---------- small helpers ----------
__device__ __forceinline__ float3 f3sub(float3 a, float3 b){ return make_float3(a.x-b.x, a.y-b.y, a.z-b.z); }
__device__ __forceinline__ float3 f3nrm(float3 v){
  float n = sqrtf(v.x*v.x + v.y*v.y + v.z*v.z);
  float inv = 1.0f / fmaxf(n, 1e-8f);
  return make_float3(v.x*inv, v.y*inv, v.z*inv);
}
__device__ __forceinline__ float3 f3cross(float3 a, float3 b){
  return make_float3(a.y*b.z - a.z*b.y, a.z*b.x - a.x*b.z, a.x*b.y - a.y*b.x);
}
__device__ __forceinline__ float silu_f(float x){
  float ex = __expf(-x);
  return x * __builtin_amdgcn_rcpf(1.0f + ex);
}
__device__ __forceinline__ uint packbf2(float a, float b){
  ushort ua = __bfloat16_as_ushort(__float2bfloat16(a));
  ushort ub = __bfloat16_as_ushort(__float2bfloat16(b));
  return (uint)ua | ((uint)ub << 16);
}

// ---------- kernel 1: residue frames ----------
__global__ void frames_kernel(const float* __restrict__ pos, float* __restrict__ frames, int Nr){
  int n = blockIdx.x*blockDim.x + threadIdx.x;
  if (n >= Nr) return;
  int k = n - 1;
  if (k < 0) k = 0;
  int kmax = Nr - 3;
  if (k > kmax) k = kmax;
  float3 p0 = make_float3(pos[3*k+0], pos[3*k+1], pos[3*k+2]);
  float3 p1 = make_float3(pos[3*k+3], pos[3*k+4], pos[3*k+5]);
  float3 p2 = make_float3(pos[3*k+6], pos[3*k+7], pos[3*k+8]);
  float3 u0 = f3nrm(f3sub(p1,p0));
  float3 u1 = f3nrm(f3sub(p2,p1));
  float3 dif = f3nrm(f3sub(u0,u1));
  float3 cr  = f3nrm(f3cross(u0,u1));
  float3 vt  = f3nrm(f3cross(dif,cr));
  float* o = frames + (size_t)n*9;
  o[0]=dif.x; o[1]=dif.y; o[2]=dif.z;
  o[3]=cr.x;  o[4]=cr.y;  o[5]=cr.z;
  o[6]=vt.x;  o[7]=vt.y;  o[8]=vt.z;
}

// ---------- kernel 2: per-edge diff + proj ----------
__global__ void edgepre_kernel(const float* __restrict__ posl, const float* __restrict__ posr,
    const int* __restrict__ el, const int* __restrict__ er, const float* __restrict__ frames,
    float* __restrict__ ediff, float* __restrict__ proj, int E){
  int e = blockIdx.x*blockDim.x + threadIdx.x;
  if (e >= E) return;
  int a = el[e], r = er[e];
  float3 pa = make_float3(posl[3*a+0], posl[3*a+1], posl[3*a+2]);
  float3 pr = make_float3(posr[3*r+0], posr[3*r+1], posr[3*r+2]);
  float3 ed = f3nrm(f3sub(pa,pr));
  const float* F = frames + (size_t)r*9;
  float px = ed.x*F[0] + ed.y*F[3] + ed.z*F[6];
  float py = ed.x*F[1] + ed.y*F[4] + ed.z*F[7];
  float pz = ed.x*F[2] + ed.y*F[5] + ed.z*F[8];
  ediff[3*e+0]=ed.x; ediff[3*e+1]=ed.y; ediff[3*e+2]=ed.z;
  proj[3*e+0]=px; proj[3*e+1]=py; proj[3*e+2]=pz;
}

// ---------- kernel W: transpose+convert weights: Wt[l][n][k] = bf16(W[l][k][n]) ----------
__global__ void wprep_kernel(const float* __restrict__ W, __hip_bfloat16* __restrict__ Wt, int total){
  int idx = blockIdx.x*blockDim.x + threadIdx.x;
  if (idx >= total) return;
  int l = idx >> 14, rem = idx & 16383, n = rem >> 7, k = rem & 127;
  Wt[idx] = __float2bfloat16(W[(l<<14) + (k<<7) + n]);
}

// ---------- kernel 3a: MFMA pre-GEMM  ligLb = bf16(lig)@W1t^T, resLb likewise ----------
__global__ __launch_bounds__(256) void pre_gemm_mfma(
    const float* __restrict__ lig, const float* __restrict__ res,
    const __hip_bfloat16* __restrict__ W1t,
    __hip_bfloat16* __restrict__ ligLb, __hip_bfloat16* __restrict__ resLb,
    int nBlkLig, int Nl, int Nr)
{
  __shared__ __hip_bfloat16 sA[64][136];
  __shared__ __hip_bfloat16 sB[128][136];
  int b = blockIdx.x;
  const float* X; __hip_bfloat16* O; int row0, rows;
  if (b < nBlkLig){ X = lig; O = ligLb; row0 = b*64;            rows = Nl; }
  else            { X = res; O = resLb; row0 = (b-nBlkLig)*64;  rows = Nr; }
  int tid = threadIdx.x;

  {
    int n = tid >> 1, c0 = (tid & 1) * 64;
    const ushort* src = (const ushort*)W1t + n*128 + c0;
    ushort* dst = (ushort*)&sB[n][0] + c0;
    #pragma unroll
    for (int i = 0; i < 64; i += 8) *(uint4*)(dst + i) = *(const uint4*)(src + i);
  }
  {
    int r = tid >> 2, p = tid & 3, cb = p*32;
    int row = row0 + r; if (row >= rows) row = rows - 1;
    const float* src = X + (size_t)row*128 + cb;
    ushort* dst = (ushort*)&sA[r][0] + cb;
    #pragma unroll
    for (int i = 0; i < 32; i += 8){
      float4 v0 = *(const float4*)(src + i);
      float4 v1 = *(const float4*)(src + i + 4);
      BU8 o;
      o.h[0]=__float2bfloat16(v0.x); o.h[1]=__float2bfloat16(v0.y);
      o.h[2]=__float2bfloat16(v0.z); o.h[3]=__float2bfloat16(v0.w);
      o.h[4]=__float2bfloat16(v1.x); o.h[5]=__float2bfloat16(v1.y);
      o.h[6]=__float2bfloat16(v1.z); o.h[7]=__float2bfloat16(v1.w);
      *(uint4*)(dst + i) = o.u;
    }
  }
  __syncthreads();

  int w = tid >> 6, l = tid & 63;
  int lrow = l & 15, lko = (l >> 4) * 8;
  f32x4 acc[4][2];
  for (int mt=0; mt<4; ++mt)
    for (int nt=0; nt<2; ++nt)
      acc[mt][nt] = (f32x4){0.f,0.f,0.f,0.f};

  #pragma unroll
  for (int kc = 0; kc < 128; kc += 32){
    bf16x8 af[4], bfr[2];
    #pragma unroll
    for (int mt=0; mt<4; ++mt)
      af[mt] = *(const bf16x8*)((const ushort*)&sA[0][0] + (mt*16+lrow)*136 + kc + lko);
    #pragma unroll
    for (int nt=0; nt<2; ++nt)
      bfr[nt] = *(const bf16x8*)((const ushort*)&sB[0][0] + (w*32+nt*16+lrow)*136 + kc + lko);
    #pragma unroll
    for (int mt=0; mt<4; ++mt){
      #pragma unroll
      for (int nt=0; nt<2; ++nt)
        acc[mt][nt] = __builtin_amdgcn_mfma_f32_16x16x32_bf16(af[mt], bfr[nt], acc[mt][nt], 0, 0, 0);
    }
  }

  int orow = (l >> 4) * 4;
  #pragma unroll
  for (int mt=0; mt<4; ++mt){
    #pragma unroll
    for (int nt=0; nt<2; ++nt){
      int n = w*32 + nt*16 + (l & 15);
      #pragma unroll
      for (int j=0; j<4; ++j){
        int row = row0 + mt*16 + orow + j;
        if (row < rows) O[(size_t)row*128 + n] = __float2bfloat16(acc[mt][nt][j]);
      }
    }
  }
}

// ---------- kernel 3b: h = silu(ligLb[el]+resLb[er]+b1) @ W2 + b2 -> bf16 (MFMA) ----------
__global__ __launch_bounds__(256) void h_gemm2_mfma(
    const __hip_bfloat16* __restrict__ ligLb, const __hip_bfloat16* __restrict__ resLb,
    const int* __restrict__ el, const int* __restrict__ er,
    const float* __restrict__ b1,
    const __hip_bfloat16* __restrict__ W2t, const float* __restrict__ b2,
    __hip_bfloat16* __restrict__ hout, int E)
{
  __shared__ __hip_bfloat16 sA[64][136];
  __shared__ __hip_bfloat16 sB[128][136];
  int tid = threadIdx.x;
  int e0 = blockIdx.x * 64;

  {
    int n = tid >> 1, c0 = (tid & 1) * 64;
    const ushort* src = (const ushort*)W2t + n*128 + c0;
    ushort* dst = (ushort*)&sB[n][0] + c0;
    #pragma unroll
    for (int i = 0; i < 64; i += 8) *(uint4*)(dst + i) = *(const uint4*)(src + i);
  }
  {
    int r = tid >> 2, p = tid & 3, cb = p*32;
    int e = e0 + r; if (e >= E) e = E - 1;
    const ushort* la = (const ushort*)ligLb + (size_t)el[e]*128 + cb;
    const ushort* ra = (const ushort*)resLb + (size_t)er[e]*128 + cb;
    ushort* dst = (ushort*)&sA[r][0] + cb;
    #pragma unroll
    for (int i = 0; i < 32; i += 8){
      BU8 A, B, O;
      A.u = *(const uint4*)(la + i);
      B.u = *(const uint4*)(ra + i);
      float4 bb0 = *(const float4*)(b1 + cb + i);
      float4 bb1 = *(const float4*)(b1 + cb + i + 4);
      float bbs[8] = {bb0.x,bb0.y,bb0.z,bb0.w,bb1.x,bb1.y,bb1.z,bb1.w};
      #pragma unroll
      for (int j=0; j<8; ++j){
        float x = __bfloat162float(A.h[j]) + __bfloat162float(B.h[j]) + bbs[j];
        O.h[j] = __float2bfloat16(silu_f(x));
      }
      *(uint4*)(dst + i) = O.u;
    }
  }
  __syncthreads();

  int w = tid >> 6, l = tid & 63;
  int lrow = l & 15, lko = (l >> 4) * 8;
  f32x4 acc[4][2];
  for (int mt=0; mt<4; ++mt)
    for (int nt=0; nt<2; ++nt)
      acc[mt][nt] = (f32x4){0.f,0.f,0.f,0.f};

  #pragma unroll
  for (int kc = 0; kc < 128; kc += 32){
    bf16x8 af[4], bfr[2];
    #pragma unroll
    for (int mt=0; mt<4; ++mt)
      af[mt] = *(const bf16x8*)((const ushort*)&sA[0][0] + (mt*16+lrow)*136 + kc + lko);
    #pragma unroll
    for (int nt=0; nt<2; ++nt)
      bfr[nt] = *(const bf16x8*)((const ushort*)&sB[0][0] + (w*32+nt*16+lrow)*136 + kc + lko);
    #pragma unroll
    for (int mt=0; mt<4; ++mt){
      #pragma unroll
      for (int nt=0; nt<2; ++nt)
        acc[mt][nt] = __builtin_amdgcn_mfma_f32_16x16x32_bf16(af[mt], bfr[nt], acc[mt][nt], 0, 0, 0);
    }
  }

  int orow = (l >> 4) * 4;
  #pragma unroll
  for (int mt=0; mt<4; ++mt){
    #pragma unroll
    for (int nt=0; nt<2; ++nt){
      int n = w*32 + nt*16 + (l & 15);
      float bb = b2[n];
      #pragma unroll
      for (int j=0; j<4; ++j){
        int e = e0 + mt*16 + orow + j;
        if (e < E) hout[(size_t)e*128 + n] = __float2bfloat16(acc[mt][nt][j] + bb);
      }
    }
  }
}

// ---------- kernel 4a: per-edge spline records ----------
// record (256B = 64 uints): [0]=h0 [1]=invD [2]=p0 [3]=pad;
// then br0: 15 intervals x {pack(c0,c1), pack(c2,c3)} (uints 4..33), br1: uints 34..63.
#define SEPB 16
#define SNIV 15
__global__ __launch_bounds__(256) void spline_kernel(
    const __hip_bfloat16* __restrict__ hbuf, const float* __restrict__ proj,
    const float* __restrict__ Wa1, const float* __restrict__ ba1,
    const float* __restrict__ Wb1, const float* __restrict__ bb1,
    const float* __restrict__ Wa2, const float* __restrict__ ba2,
    const float* __restrict__ Wb2, const float* __restrict__ bb2,
    uint* __restrict__ table, int E)
{
  __shared__ float sA[2][SEPB][33];     // padded: node-phase reads conflict-free
  __shared__ float sBA[2][32], sWB[2][32];
  __shared__ float sNF[SEPB][2][16], sND[SEPB][2][16];
  __shared__ float sMin[SEPB], sMax[SEPB];
  __shared__ float sH0[SEPB], sDv[SEPB];
  __shared__ uint  sRec[SEPB][64];

  int tid = threadIdx.x;
  int eb0 = blockIdx.x * SEPB;

  // P1: per-edge min/max over 128 h (16 threads/edge x bf16x8)
  {
    int et = tid >> 4, sg = tid & 15;
    int e = eb0 + et; if (e >= E) e = E-1;
    const ushort* hp = (const ushort*)hbuf + (size_t)e*128 + sg*8;
    uint4 raw = *(const uint4*)hp;
    uint us[4] = {raw.x, raw.y, raw.z, raw.w};
    float mn = 1e30f, mx = -1e30f;
    #pragma unroll
    for (int i=0;i<4;i++){
      float lo = __uint_as_float(us[i]<<16);
      float hi = __uint_as_float(us[i]&0xFFFF0000u);
      mn = fminf(mn, fminf(lo,hi)); mx = fmaxf(mx, fmaxf(lo,hi));
    }
    #pragma unroll
    for (int o=8;o>0;o>>=1){ mn=fminf(mn,__shfl_xor(mn,o)); mx=fmaxf(mx,__shfl_xor(mx,o)); }
    if (sg==0){ sMin[et]=mn; sMax[et]=mx; }
  }
  if (tid < 64){
    int br = tid>>5, q = tid&31;
    sBA[br][q] = br ? ba2[q] : ba1[q];
    sWB[br][q] = br ? Wb2[q] : Wb1[q];
  }
  __syncthreads();

  // P1b: per-edge A_q (1024 tasks) + scalars
  for (int t=tid; t<2*SEPB*32; t+=256){
    int et = t>>6, rem = t&63, br = rem>>5, q = rem&31;
    int e = eb0+et; if (e>=E) e=E-1;
    const float* Wa = br ? Wa2 : Wa1;
    float p0=proj[3*e], p1=proj[3*e+1], p2=proj[3*e+2];
    sA[br][et][q] = p0*Wa[q]+p1*Wa[32+q]+p2*Wa[64+q];
  }
  if (tid < SEPB){
    int e = eb0+tid; if (e>=E) e=E-1;
    float range = fmaxf(sMax[tid]-sMin[tid], 1e-3f);
    float Dv = range*(1.0f/SNIV);
    sH0[tid]=sMin[tid]; sDv[tid]=Dv;
    sRec[tid][0]=__float_as_uint(sMin[tid]);
    sRec[tid][1]=__float_as_uint((float)SNIV/range);
    sRec[tid][2]=__float_as_uint(proj[3*e]);
    sRec[tid][3]=0u;
  }
  __syncthreads();

  // P2: exact f,f' at 16 nodes (512 tasks, 2/thread)
  for (int t=tid; t<SEPB*32; t+=256){
    int et = t>>5, rem = t&31, br = rem>>4, nd = rem&15;
    float hn = fmaf((float)nd, sDv[et], sH0[et]);
    float f = 0.f, fd = 0.f;
    #pragma unroll 8
    for (int q = 0; q < 32; ++q){
      float a = sA[br][et][q], b = sBA[br][q], w = sWB[br][q];
      float x  = fmaf(hn, a, b);
      float ex = __expf(-x);
      float sg = __builtin_amdgcn_rcpf(1.0f + ex);
      f  = fmaf(w, x*sg, f);
      float sp = sg * fmaf(x, 1.0f - sg, 1.0f);
      fd = fmaf(w*a, sp, fd);
    }
    sNF[et][br][nd] = f;
    sND[et][br][nd] = fd;
  }
  __syncthreads();

  // P2.5: Hermite cubic coeffs -> packed bf16 into record image
  for (int t=tid; t<SEPB*32; t+=256){
    int et = t>>5, rem = t&31, br = rem>>4, i = rem&15;
    if (i < SNIV){
      float Dv = sDv[et];
      float f0 = sNF[et][br][i],    f1 = sNF[et][br][i+1];
      float g0 = sND[et][br][i]*Dv, g1 = sND[et][br][i+1]*Dv;
      float bb = br ? bb2[0] : bb1[0];
      float df = f1 - f0;
      float c0 = f0 + bb, c1 = g0;
      float c2 = 3.f*df - 2.f*g0 - g1;
      float c3 = g0 + g1 - 2.f*df;
      sRec[et][4 + br*30 + 2*i]     = packbf2(c0, c1);
      sRec[et][4 + br*30 + 2*i + 1] = packbf2(c2, c3);
    }
  }
  __syncthreads();

  // copy records out (one uint4 per thread)
  {
    int rec = tid >> 4, part = tid & 15;
    int e = eb0 + rec; if (e >= E) e = E-1;
    *(uint4*)(table + (size_t)e*64 + part*4) = *(const uint4*)&sRec[rec][part*4];
  }
}

// ---------- kernel 4b: per-atom fused spline-eval + segmented reduce ----------
__global__ __launch_bounds__(128) void reduce_kernel(
    const __hip_bfloat16* __restrict__ hbuf, const uint* __restrict__ table,
    const float* __restrict__ ediff, const int* __restrict__ el,
    float* __restrict__ lv, int E, int layer)
{
  __shared__ uint sTab[64][64];     // 16 KB: 64 edge records
  __shared__ float sEd[64][3];
  int a = blockIdx.x;
  int d = threadIdx.x;

  int lo = 0, hi = E;
  while (lo < hi){ int m = (lo+hi)>>1; if (el[m] < a) lo = m+1; else hi = m; }
  int estart = lo;
  int lo2 = lo, hi2 = E;
  while (lo2 < hi2){ int m = (lo2+hi2)>>1; if (el[m] <= a) lo2 = m+1; else hi2 = m; }
  int eend = lo2;

  float sumw = 0.f, tx = 0.f, ty = 0.f, tz = 0.f;

  for (int ebase = estart; ebase < eend; ebase += 64){
    int n = min(64, eend - ebase);
    __syncthreads();
    for (int t = d; t < n*16; t += 128){
      int rec = t>>4, part = t&15;
      *(uint4*)&sTab[rec][part<<2] = *(const uint4*)(table + (size_t)(ebase+rec)*64 + (part<<2));
    }
    for (int t = d; t < n*3; t += 128)
      ((float*)sEd)[t] = ediff[(size_t)ebase*3 + t];
    __syncthreads();

    #pragma unroll 4
    for (int ei = 0; ei < n; ++ei){
      float h = __bfloat162float(hbuf[(size_t)(ebase+ei)*128 + d]);
      const uint* rec = &sTab[ei][0];
      float h0   = __uint_as_float(rec[0]);
      float invD = __uint_as_float(rec[1]);
      float p0   = __uint_as_float(rec[2]);
      float sf = (h - h0) * invD;
      int ii = (int)sf; ii = ii < 0 ? 0 : (ii > SNIV-1 ? SNIV-1 : ii);
      float s = sf - (float)ii;
      uint u0 = rec[4 + 2*ii],  u1 = rec[5 + 2*ii];
      uint u2 = rec[34 + 2*ii], u3 = rec[35 + 2*ii];
      float c0 = __uint_as_float(u0<<16), c1 = __uint_as_float(u0&0xFFFF0000u);
      float c2 = __uint_as_float(u1<<16), c3 = __uint_as_float(u1&0xFFFF0000u);
      float v1 = fmaf(fmaf(fmaf(c3,s,c2),s,c1),s,c0);
      float e0 = __uint_as_float(u2<<16), e1 = __uint_as_float(u2&0xFFFF0000u);
      float e2 = __uint_as_float(u3<<16), e3 = __uint_as_float(u3&0xFFFF0000u);
      float v2 = fmaf(fmaf(fmaf(e3,s,e2),s,e1),s,e0);
      float hp = h * p0;
      float w1 = v1 + hp, w2v = v2 + hp;
      sumw += w1;
      tx = fmaf(sEd[ei][0], w2v, tx);
      ty = fmaf(sEd[ei][1], w2v, ty);
      tz = fmaf(sEd[ei][2], w2v, tz);
    }
  }

  size_t base = (size_t)a*384 + d;
  if (layer == 0){
    lv[base      ] = tx;
    lv[base + 128] = ty;
    lv[base + 256] = tz;
  } else {
    float m = 1.0f + sumw;
    lv[base      ] = lv[base      ]*m + tx;
    lv[base + 128] = lv[base + 128]*m + ty;
    lv[base + 256] = lv[base + 256]*m + tz;
  }
}

// ---------- kernel 5: head ----------
__global__ __launch_bounds__(128) void head_kernel(
    const float* __restrict__ lv, const float* __restrict__ Wl1, const float* __restrict__ bl1,
    const float* __restrict__ Wl2, const float* __restrict__ bl2,
    const float* __restrict__ lvin, float* __restrict__ out, int Nl)
{
  int a = blockIdx.x, d = threadIdx.x;
  __shared__ float slv[3][128];
  __shared__ float sred[2][3];
  size_t base = (size_t)a*384;
  slv[0][d] = lv[base + d];
  slv[1][d] = lv[base + 128 + d];
  slv[2][d] = lv[base + 256 + d];
  __syncthreads();
  float b = bl1[d];
  float a0 = b, a1 = b, a2 = b;
  #pragma unroll 4
  for (int k = 0; k < 128; ++k) {
    float w = Wl1[k*128 + d];
    a0 = fmaf(slv[0][k], w, a0);
    a1 = fmaf(slv[1][k], w, a1);
    a2 = fmaf(slv[2][k], w, a2);
  }
  float wl2 = Wl2[d];
  float z0 = fmaxf(a0, 0.f)*wl2;
  float z1 = fmaxf(a1, 0.f)*wl2;
  float z2 = fmaxf(a2, 0.f)*wl2;
  #pragma unroll
  for (int off = 32; off > 0; off >>= 1) {
    z0 += __shfl_down(z0, off);
    z1 += __shfl_down(z1, off);
    z2 += __shfl_down(z2, off);
  }
  int wv = d >> 6;
  if ((d & 63) == 0) { sred[wv][0]=z0; sred[wv][1]=z1; sred[wv][2]=z2; }
  __syncthreads();
  if (d == 0) {
    float bb = bl2[0];
    out[a*3+0] = sred[0][0]+sred[1][0] + bb + lvin[a*3+0];
    out[a*3+1] = sred[0][1]+sred[1][1] + bb + lvin[a*3+1];
    out[a*3+2] = sred[0][2]+sred[1][2] + bb + lvin[a*3+2];
  }
}

// ---------- launcher ----------
extern "C" void kernel_launch(void* const* d_in, const int* in_sizes, int n_in,
                              void* d_out, int out_size, void* d_ws, size_t ws_size,
                              hipStream_t stream)
{
  const float* lig   = (const float*)d_in[0];
  const float* lvin  = (const float*)d_in[1];
  const float* posl  = (const float*)d_in[2];
  const float* res   = (const float*)d_in[3];
  const float* posr  = (const float*)d_in[4];
  const int*   el    = (const int*)d_in[7];
  const int*   er    = (const int*)d_in[8];
  const float* Win1  = (const float*)d_in[9];
  const float* bin1  = (const float*)d_in[10];
  const float* Win2  = (const float*)d_in[11];
  const float* bin2  = (const float*)d_in[12];
  const float* Ws1a  = (const float*)d_in[13];
  const float* bs1a  = (const float*)d_in[14];
  const float* Ws1b  = (const float*)d_in[15];
  const float* bs1b  = (const float*)d_in[16];
  const float* Ws2a  = (const float*)d_in[17];
  const float* bs2a  = (const float*)d_in[18];
  const float* Ws2b  = (const float*)d_in[19];
  const float* bs2b  = (const float*)d_in[20];
  const float* Wl1   = (const float*)d_in[21];
  const float* bl1   = (const float*)d_in[22];
  const float* Wl2   = (const float*)d_in[23];
  const float* bl2   = (const float*)d_in[24];

  int Nl = in_sizes[2] / 3;
  int Nr = in_sizes[4] / 3;
  int E  = in_sizes[7];

  char* wsb = (char*)d_ws;
  size_t off = 0;
  auto carve = [&](size_t bytes) -> char* {
    char* p = wsb + off;
    off += (bytes + 255) & ~(size_t)255;
    return p;
  };
  float* frames = (float*)carve((size_t)Nr*9*4);
  float* ediff  = (float*)carve((size_t)E*3*4);
  float* proj   = (float*)carve((size_t)E*3*4);
  __hip_bfloat16* hbuf  = (__hip_bfloat16*)carve((size_t)E*128*2);
  uint* table   = (uint*)carve((size_t)E*256);
  float* lvbuf  = (float*)carve((size_t)Nl*384*4);
  __hip_bfloat16* ligLb = (__hip_bfloat16*)carve((size_t)Nl*128*2);
  __hip_bfloat16* resLb = (__hip_bfloat16*)carve((size_t)Nr*128*2);
  __hip_bfloat16* W1t   = (__hip_bfloat16*)carve((size_t)2*16384*2);
  __hip_bfloat16* W2t   = (__hip_bfloat16*)carve((size_t)2*16384*2);

  int nBlkLig = (Nl + 63)/64;
  int nBlkRes = (Nr + 63)/64;

  hipLaunchKernelGGL(frames_kernel, dim3((Nr+255)/256), dim3(256), 0, stream, posr, frames, Nr);
  hipLaunchKernelGGL(edgepre_kernel, dim3((E+255)/256), dim3(256), 0, stream,
                     posl, posr, el, er, frames, ediff, proj, E);
  hipLaunchKernelGGL(wprep_kernel, dim3((2*16384+255)/256), dim3(256), 0, stream, Win1, W1t, 2*16384);
  hipLaunchKernelGGL(wprep_kernel, dim3((2*16384+255)/256), dim3(256), 0, stream, Win2, W2t, 2*16384);

  for (int l = 0; l < 2; ++l) {
    hipLaunchKernelGGL(pre_gemm_mfma, dim3(nBlkLig+nBlkRes), dim3(256), 0, stream,
        lig, res, W1t + (size_t)l*16384, ligLb, resLb, nBlkLig, Nl, Nr);
    hipLaunchKernelGGL(h_gemm2_mfma, dim3((E+63)/64), dim3(256), 0, stream,
        ligLb, resLb, el, er,
        bin1 + (size_t)l*128,
        W2t + (size_t)l*16384, bin2 + (size_t)l*128,
        hbuf, E);
    hipLaunchKernelGGL(spline_kernel, dim3((E+SEPB-1)/SEPB), dim3(256), 0, stream,
        hbuf, proj,
        Ws1a + (size_t)l*96, bs1a + (size_t)l*32, Ws1b + (size_t)l*32, bs1b + l,
        Ws2a + (size_t)l*96, bs2a + (size_t)l*32, Ws2b + (size_t)l*32, bs2b + l,
        table, E);
    hipLaunchKernelGGL(reduce_kernel, dim3(Nl), dim3(128), 0, stream,
        hbuf, table, ediff, el, lvbuf, E, l);
  }
  hipLaunchKernelGGL(head_kernel, dim3(Nl), dim3(128), 0, stream,
                     lvbuf, Wl1, bl1, Wl2, bl2, lvin, (float*)d_out, Nl);
}